// Round 5
// baseline (603.662 us; speedup 1.0000x reference)
//
#include <hip/hip_runtime.h>
#include <hip/hip_bf16.h>
#include <math.h>

#define DIMV 512
#define NTOK 16384   // B*P*N = 2*8*1024
#define NSEQ 1024
#define HEADSV 8
#define PPV 8
#define DHEAD 64
#define QKVW 1536
#define HIDV 2048

typedef unsigned short ushort;
typedef __attribute__((ext_vector_type(8))) short short8;
typedef __attribute__((ext_vector_type(8))) unsigned short ushort8;
typedef __attribute__((ext_vector_type(4))) float floatx4;

__device__ __forceinline__ float bf2f(ushort u){
  union { unsigned int i; float f; } c; c.i = ((unsigned int)u) << 16; return c.f;
}
__device__ __forceinline__ ushort f2bf(float f){
  __hip_bfloat16 h = __float2bfloat16(f);
  ushort u; __builtin_memcpy(&u, &h, 2); return u;
}
__device__ __forceinline__ void async_copy16(const void* gptr, void* lptr){
  __builtin_amdgcn_global_load_lds((const __attribute__((address_space(1))) void*)gptr,
                                   (__attribute__((address_space(3))) void*)lptr, 16, 0, 0);
}
// tanh-form GELU via one v_exp_f32: x * sigmoid(1.5957691x + 0.0713548x^3)
__device__ __forceinline__ float fast_gelu(float x){
  float u = x * (2.3022084f + 0.1029435f * x * x);   // (2u)*log2(e)
  return x * __builtin_amdgcn_rcpf(1.f + exp2f(-u));
}

__device__ __forceinline__ void wave_reduce2(float& a, float& b){
  #pragma unroll
  for (int off = 32; off > 0; off >>= 1){
    a += __shfl_down(a, off, 64);
    b += __shfl_down(b, off, 64);
  }
}

// One block per token row: x -> LN0 -> x1 (fp32), LN1 -> h (bf16)
__global__ __launch_bounds__(256) void ln2_kernel(const float* __restrict__ x,
    const float* __restrict__ w0, const float* __restrict__ b0,
    const float* __restrict__ w1, const float* __restrict__ b1,
    float* __restrict__ x1, __hip_bfloat16* __restrict__ h){
  __shared__ float sm[16];
  size_t row = blockIdx.x;
  int t = threadIdx.x;
  const float2* xr = (const float2*)(x + row * DIMV);
  float2 v = xr[t];
  float s = v.x + v.y;
  float sq = v.x * v.x + v.y * v.y;
  wave_reduce2(s, sq);
  int wid = t >> 6, lane = t & 63;
  if (lane == 0){ sm[wid] = s; sm[8 + wid] = sq; }
  __syncthreads();
  s  = sm[0] + sm[1] + sm[2] + sm[3];
  sq = sm[8] + sm[9] + sm[10] + sm[11];
  float mu = s * (1.f / DIMV);
  float var = sq * (1.f / DIMV) - mu * mu;
  float r = rsqrtf(var + 1e-5f);
  float2 ww = ((const float2*)w0)[t];
  float2 bb = ((const float2*)b0)[t];
  float2 y;
  y.x = (v.x - mu) * r * ww.x + bb.x;
  y.y = (v.y - mu) * r * ww.y + bb.y;
  ((float2*)(x1 + row * DIMV))[t] = y;
  float s2 = y.x + y.y, sq2 = y.x * y.x + y.y * y.y;
  wave_reduce2(s2, sq2);
  __syncthreads();
  if (lane == 0){ sm[wid] = s2; sm[8 + wid] = sq2; }
  __syncthreads();
  s2  = sm[0] + sm[1] + sm[2] + sm[3];
  sq2 = sm[8] + sm[9] + sm[10] + sm[11];
  float mu2 = s2 * (1.f / DIMV);
  float var2 = sq2 * (1.f / DIMV) - mu2 * mu2;
  float r2 = rsqrtf(var2 + 1e-5f);
  float2 w1v = ((const float2*)w1)[t];
  float2 b1v = ((const float2*)b1)[t];
  float hx = (y.x - mu2) * r2 * w1v.x + b1v.x;
  float hy = (y.y - mu2) * r2 * w1v.y + b1v.y;
  ushort2 hb; hb.x = f2bf(hx); hb.y = f2bf(hy);
  ((ushort2*)(h + row * DIMV))[t] = hb;
}

// Transpose fp32 W[K,N] -> bf16 Wt[N,K]
__global__ __launch_bounds__(256) void wtrans_kernel(const float* __restrict__ W,
    __hip_bfloat16* __restrict__ Wt, int K, int N){
  __shared__ float tile[32][33];
  int bn = blockIdx.x * 32;
  int bk = blockIdx.y * 32;
  int tx = threadIdx.x, ty = threadIdx.y;
  #pragma unroll
  for (int i = 0; i < 32; i += 8)
    tile[ty + i][tx] = W[(size_t)(bk + ty + i) * N + bn + tx];
  __syncthreads();
  #pragma unroll
  for (int i = 0; i < 32; i += 8)
    Wt[(size_t)(bn + ty + i) * K + bk + tx] = __float2bfloat16(tile[tx][ty + i]);
}

// Transpose V per (b,hh,p) slice: qkv V-part [n,64] -> vt[slice][d=64][n=1024]
__global__ __launch_bounds__(256) void vtrans_kernel(const __hip_bfloat16* __restrict__ qkvp,
                                                     ushort* __restrict__ vt){
  __shared__ ushort T[64 * 72];
  int sidx = blockIdx.x >> 4;          // b*64 + hh*8 + p
  int n0 = (blockIdx.x & 15) * 64;
  int b = sidx >> 6, hh = (sidx >> 3) & 7, p = sidx & 7;
  const ushort* vbase = (const ushort*)qkvp + (size_t)(b * PPV + p) * NSEQ * QKVW + 1024 + hh * DHEAD;
  int t = threadIdx.x;
  int r = t >> 2, c16 = (t & 3) * 16;
  const ushort* g = vbase + (size_t)(n0 + r) * QKVW + c16;
  *(short8*)&T[r * 72 + c16]     = *(const short8*)g;
  *(short8*)&T[r * 72 + c16 + 8] = *(const short8*)(g + 8);
  __syncthreads();
  int d = t >> 2, m16 = (t & 3) * 16;
  ushort* o = vt + (size_t)sidx * 65536 + (size_t)d * 1024 + n0 + m16;
  ushort tmp[16];
  #pragma unroll
  for (int j = 0; j < 16; j++) tmp[j] = T[(m16 + j) * 72 + d];
  *(short8*)o       = *(short8*)tmp;
  *(short8*)(o + 8) = *(short8*)(tmp + 8);
}

// MFMA bf16 GEMM v2: C = A[M,K] @ Bt[N,K]^T (+bias)(gelu?)(+Rf fp32 | +Rb bf16)
// 128x128 tile, BK=64, XOR-swizzled 16B staging blocks (global-side swizzle).
__global__ __launch_bounds__(256) void gemm_mfma(
    const __hip_bfloat16* __restrict__ A,
    const __hip_bfloat16* __restrict__ Bt,
    const float* __restrict__ bias,
    const float* __restrict__ Rf,
    const __hip_bfloat16* __restrict__ Rb,
    float* __restrict__ Cf,
    __hip_bfloat16* __restrict__ Cb,
    int M, int N, int K, int dogelu)
{
  __shared__ ushort As[128 * 64];   // 16 KB, row stride 128B, 16B blocks swizzled
  __shared__ ushort Bs[128 * 64];
  int tid = threadIdx.x;
  int w = tid >> 6, l = tid & 63;
  size_t bm = (size_t)blockIdx.y * 128, bn = (size_t)blockIdx.x * 128;
  int wm = (w & 1) * 64, wn = (w >> 1) * 64;

  // staging: issue i covers rows i*32 + w*8 + (l>>3); global col-block = (l&7)^(row&7)
  int lrow = l >> 3;                       // 0..7  (== row&7)
  int srow = w * 8 + lrow;                 // 0..31
  int gswz = ((l & 7) ^ lrow) * 8;         // swizzled global col (elems)
  const ushort* Agp = (const ushort*)A  + (bm + srow) * K + gswz;
  const ushort* Bgp = (const ushort*)Bt + (bn + srow) * K + gswz;
  ushort* lA = &As[srow * 64 + (l & 7) * 8];
  ushort* lB = &Bs[srow * 64 + (l & 7) * 8];

  floatx4 acc[4][4] = {};
  int fm = l & 15;                         // fragment row within 16
  int quad = l >> 4;
  int fsw = fm & 7;

  for (int k0 = 0; k0 < K; k0 += 64){
    #pragma unroll
    for (int i = 0; i < 4; i++){
      async_copy16(Agp + (size_t)(i * 32) * K + k0, lA + i * 32 * 64);
      async_copy16(Bgp + (size_t)(i * 32) * K + k0, lB + i * 32 * 64);
    }
    __syncthreads();
    #pragma unroll
    for (int kq = 0; kq < 2; kq++){
      short8 af[4], bf[4];
      #pragma unroll
      for (int i = 0; i < 4; i++){
        int ra = wm + i * 16 + fm;
        int rb = wn + i * 16 + fm;
        af[i] = *(const short8*)&As[ra * 64 + (((kq * 4 + quad) ^ fsw)) * 8];
        bf[i] = *(const short8*)&Bs[rb * 64 + (((kq * 4 + quad) ^ fsw)) * 8];
      }
      #pragma unroll
      for (int mi = 0; mi < 4; mi++)
        #pragma unroll
        for (int ni = 0; ni < 4; ni++)
          acc[mi][ni] = __builtin_amdgcn_mfma_f32_16x16x32_bf16(af[mi], bf[ni], acc[mi][ni], 0, 0, 0);
    }
    __syncthreads();
  }

  // C/D layout: col = l&15, row = quad*4 + reg
  int rq = quad * 4;
  #pragma unroll
  for (int ni = 0; ni < 4; ni++){
    size_t col = bn + wn + ni * 16 + fm;
    float bv = bias ? bias[col] : 0.f;
    #pragma unroll
    for (int mi = 0; mi < 4; mi++){
      #pragma unroll
      for (int r = 0; r < 4; r++){
        size_t row = bm + wm + mi * 16 + rq + r;
        float v = acc[mi][ni][r] + bv;
        if (dogelu) v = fast_gelu(v);
        size_t idx = row * N + col;
        if (Rf) v += Rf[idx];
        if (Rb) v += bf2f(((const ushort*)Rb)[idx]);
        if (Cf) Cf[idx] = v;
        if (Cb) Cb[idx] = __float2bfloat16(v);
      }
    }
  }
}

// MFMA flash attention v2 (unchanged from round 4).
#define SC2 0.18033688011112042f   // 0.125 * log2(e)
__global__ __launch_bounds__(256) void attn_mfma(const __hip_bfloat16* __restrict__ qkvp,
                                                 const ushort* __restrict__ vt,
                                                 __hip_bfloat16* __restrict__ outp){
  __shared__ ushort Ks[64 * 64];
  __shared__ ushort Vs[64 * 64];
  __shared__ ushort Ps[4][32 * 72];
  int tid = threadIdx.x;
  int w = tid >> 6, l = tid & 63;
  int r15 = l & 15, quad = l >> 4, fq = quad * 8;
  int slice = blockIdx.x & 127;
  int qc = blockIdx.x >> 7;
  int b = slice >> 6, hh = (slice >> 3) & 7, p = slice & 7;
  const ushort* base = (const ushort*)qkvp + (size_t)(b * PPV + p) * NSEQ * QKVW;
  const ushort* kb = base + 512 + hh * DHEAD;
  const ushort* vb = vt + (size_t)slice * 65536;

  int q0 = qc * 128 + w * 32;
  short8 qf[2][2];
  #pragma unroll
  for (int mi = 0; mi < 2; mi++)
    #pragma unroll
    for (int kk = 0; kk < 2; kk++)
      qf[mi][kk] = *(const short8*)(base + (size_t)(q0 + mi * 16 + r15) * QKVW + hh * DHEAD + kk * 32 + fq);

  floatx4 o[2][4] = {};
  floatx4 lacc[2] = {};
  short8 ones;
  #pragma unroll
  for (int j = 0; j < 8; j++) ones[j] = (short)0x3F80;

  int s0 = w * 64 + l, s1 = 256 + w * 64 + l;
  int row0 = s0 >> 3, row1 = s1 >> 3;
  int gc0 = (s0 & 7) ^ (row0 & 7), gc1 = (s1 & 7) ^ (row1 & 7);
  const ushort* kp0 = kb + (size_t)row0 * QKVW + gc0 * 8;
  const ushort* kp1 = kb + (size_t)row1 * QKVW + gc1 * 8;
  const ushort* vp0 = vb + (size_t)row0 * 1024 + gc0 * 8;
  const ushort* vp1 = vb + (size_t)row1 * 1024 + gc1 * 8;
  ushort* kd0 = &Ks[s0 * 8]; ushort* kd1 = &Ks[s1 * 8];
  ushort* vd0 = &Vs[s0 * 8]; ushort* vd1 = &Vs[s1 * 8];

  int sw = r15 & 7;

  for (int m0 = 0; m0 < NSEQ; m0 += 64){
    async_copy16(kp0 + (size_t)m0 * QKVW, kd0);
    async_copy16(kp1 + (size_t)m0 * QKVW, kd1);
    async_copy16(vp0 + m0, vd0);
    async_copy16(vp1 + m0, vd1);
    __syncthreads();

    floatx4 s[2][4] = {};
    #pragma unroll
    for (int ni = 0; ni < 4; ni++){
      int row = ni * 16 + r15;
      short8 kf0 = *(const short8*)&Ks[row * 64 + (quad ^ sw) * 8];
      short8 kf1 = *(const short8*)&Ks[row * 64 + ((4 + quad) ^ sw) * 8];
      #pragma unroll
      for (int mi = 0; mi < 2; mi++){
        s[mi][ni] = __builtin_amdgcn_mfma_f32_16x16x32_bf16(qf[mi][0], kf0, s[mi][ni], 0, 0, 0);
        s[mi][ni] = __builtin_amdgcn_mfma_f32_16x16x32_bf16(qf[mi][1], kf1, s[mi][ni], 0, 0, 0);
      }
    }

    #pragma unroll
    for (int mi = 0; mi < 2; mi++)
      #pragma unroll
      for (int ni = 0; ni < 4; ni++)
        #pragma unroll
        for (int r = 0; r < 4; r++){
          float pv = exp2f(s[mi][ni][r] * SC2);
          Ps[w][(mi * 16 + quad * 4 + r) * 72 + ni * 16 + r15] = f2bf(pv);
        }

    short8 pf[2][2];
    #pragma unroll
    for (int mi = 0; mi < 2; mi++)
      #pragma unroll
      for (int kk = 0; kk < 2; kk++)
        pf[mi][kk] = *(const short8*)&Ps[w][(mi * 16 + r15) * 72 + kk * 32 + fq];

    #pragma unroll
    for (int mi = 0; mi < 2; mi++)
      #pragma unroll
      for (int kk = 0; kk < 2; kk++)
        lacc[mi] = __builtin_amdgcn_mfma_f32_16x16x32_bf16(pf[mi][kk], ones, lacc[mi], 0, 0, 0);

    #pragma unroll
    for (int dj = 0; dj < 4; dj++){
      int d = dj * 16 + r15;
      #pragma unroll
      for (int kk = 0; kk < 2; kk++){
        short8 vf = *(const short8*)&Vs[d * 64 + (((kk * 4 + quad)) ^ sw) * 8];
        #pragma unroll
        for (int mi = 0; mi < 2; mi++)
          o[mi][dj] = __builtin_amdgcn_mfma_f32_16x16x32_bf16(pf[mi][kk], vf, o[mi][dj], 0, 0, 0);
      }
    }
    __syncthreads();
  }

  #pragma unroll
  for (int mi = 0; mi < 2; mi++){
    #pragma unroll
    for (int r = 0; r < 4; r++){
      float inv = 1.f / lacc[mi][r];
      size_t n = q0 + mi * 16 + quad * 4 + r;
      ushort* orow = (ushort*)outp + ((size_t)((b * HEADSV + hh) * NSEQ + n)) * DIMV + p * DHEAD;
      #pragma unroll
      for (int dj = 0; dj < 4; dj++)
        orow[dj * 16 + r15] = f2bf(o[mi][dj][r] * inv);
    }
  }
}

extern "C" void kernel_launch(void* const* d_in, const int* in_sizes, int n_in,
                              void* d_out, int out_size, void* d_ws, size_t ws_size,
                              hipStream_t stream){
  (void)in_sizes; (void)n_in; (void)out_size; (void)ws_size;
  const float* x    = (const float*)d_in[0];
  const float* lw0  = (const float*)d_in[1];
  const float* lb0  = (const float*)d_in[2];
  const float* lw1  = (const float*)d_in[3];
  const float* lb1  = (const float*)d_in[4];
  const float* wqkv = (const float*)d_in[5];
  const float* wo   = (const float*)d_in[6];
  const float* bo   = (const float*)d_in[7];
  const float* w1   = (const float*)d_in[8];
  const float* b1   = (const float*)d_in[9];
  const float* w2   = (const float*)d_in[10];
  const float* b2   = (const float*)d_in[11];
  float* out = (float*)d_out;
  char* ws = (char*)d_ws;
  const size_t MB = 1024 * 1024;

  // Workspace (peak 152 MB):
  // [0,32)    x1 fp32 (LN0 out; residual for wo-GEMM)
  // [32,64)   vt (16MB, dead after attn)
  // [64,80)   x2b bf16 (wo-GEMM out; residual for final GEMM)
  // [80,87)   transposed bf16 weights
  // [88,104)  h bf16 -> attnB bf16
  // [104,152) qkv bf16; tB spans [88,152) later
  float* x1            = (float*)(ws);
  ushort* vtbuf        = (ushort*)(ws + 32 * MB);
  __hip_bfloat16* x2b  = (__hip_bfloat16*)(ws + 64 * MB);
  __hip_bfloat16* wqkvT= (__hip_bfloat16*)(ws + 80 * MB);
  __hip_bfloat16* woT  = (__hip_bfloat16*)(ws + 82 * MB);
  __hip_bfloat16* w1T  = (__hip_bfloat16*)(ws + 83 * MB);
  __hip_bfloat16* w2T  = (__hip_bfloat16*)(ws + 85 * MB);
  __hip_bfloat16* hB   = (__hip_bfloat16*)(ws + 88 * MB);
  __hip_bfloat16* attnB= hB;
  __hip_bfloat16* qkvB = (__hip_bfloat16*)(ws + 104 * MB);
  __hip_bfloat16* tB   = (__hip_bfloat16*)(ws + 88 * MB);

  wtrans_kernel<<<dim3(48, 16), dim3(32, 8), 0, stream>>>(wqkv, wqkvT, 512, 1536);
  wtrans_kernel<<<dim3(16, 16), dim3(32, 8), 0, stream>>>(wo,   woT,   512, 512);
  wtrans_kernel<<<dim3(64, 16), dim3(32, 8), 0, stream>>>(w1,   w1T,   512, 2048);
  wtrans_kernel<<<dim3(16, 64), dim3(32, 8), 0, stream>>>(w2,   w2T,   2048, 512);

  ln2_kernel<<<NTOK, 256, 0, stream>>>(x, lw0, lb0, lw1, lb1, x1, hB);

  // qkv = h @ w_qkv -> bf16
  gemm_mfma<<<dim3(QKVW / 128, NTOK / 128), 256, 0, stream>>>(
      hB, wqkvT, nullptr, nullptr, nullptr, nullptr, qkvB, NTOK, QKVW, DIMV, 0);

  vtrans_kernel<<<2048, 256, 0, stream>>>(qkvB, vtbuf);

  attn_mfma<<<1024, 256, 0, stream>>>(qkvB, vtbuf, attnB);

  // x2b = attn @ w_o + b_o + x1 (fp32 residual) -> bf16 only
  gemm_mfma<<<dim3(DIMV / 128, NTOK / 128), 256, 0, stream>>>(
      attnB, woT, bo, x1, nullptr, nullptr, x2b, NTOK, DIMV, DIMV, 0);

  // t = gelu_fast(x2b @ w1 + b1) -> bf16
  gemm_mfma<<<dim3(HIDV / 128, NTOK / 128), 256, 0, stream>>>(
      x2b, w1T, b1, nullptr, nullptr, nullptr, tB, NTOK, HIDV, DIMV, 1);

  // out = t @ w2 + b2 + x2b (bf16 residual) -> fp32
  gemm_mfma<<<dim3(DIMV / 128, NTOK / 128), 256, 0, stream>>>(
      tB, w2T, b2, nullptr, x2b, out, nullptr, NTOK, DIMV, HIDV, 0);
}

// Round 6
// 461.756 us; speedup vs baseline: 1.3073x; 1.3073x over previous
//
#include <hip/hip_runtime.h>
#include <hip/hip_bf16.h>
#include <math.h>

#define DIMV 512
#define NTOK 16384   // B*P*N = 2*8*1024
#define NSEQ 1024
#define HEADSV 8
#define PPV 8
#define DHEAD 64
#define QKVW 1536
#define HIDV 2048

typedef unsigned short ushort;
typedef __attribute__((ext_vector_type(8))) short short8;
typedef __attribute__((ext_vector_type(8))) unsigned short ushort8;
typedef __attribute__((ext_vector_type(4))) float floatx4;

__device__ __forceinline__ float bf2f(ushort u){
  union { unsigned int i; float f; } c; c.i = ((unsigned int)u) << 16; return c.f;
}
__device__ __forceinline__ ushort f2bf(float f){
  __hip_bfloat16 h = __float2bfloat16(f);
  ushort u; __builtin_memcpy(&u, &h, 2); return u;
}
__device__ __forceinline__ void async_copy16(const void* gptr, void* lptr){
  __builtin_amdgcn_global_load_lds((const __attribute__((address_space(1))) void*)gptr,
                                   (__attribute__((address_space(3))) void*)lptr, 16, 0, 0);
}
// tanh-form GELU via one v_exp_f32: x * sigmoid(1.5957691x + 0.0713548x^3)
__device__ __forceinline__ float fast_gelu(float x){
  float u = x * (2.3022084f + 0.1029435f * x * x);   // (2u)*log2(e)
  return x * __builtin_amdgcn_rcpf(1.f + exp2f(-u));
}

__device__ __forceinline__ void wave_reduce2(float& a, float& b){
  #pragma unroll
  for (int off = 32; off > 0; off >>= 1){
    a += __shfl_down(a, off, 64);
    b += __shfl_down(b, off, 64);
  }
}

// One block per token row: x -> LN0 -> x1 (fp32), LN1 -> h (bf16)
__global__ __launch_bounds__(256) void ln2_kernel(const float* __restrict__ x,
    const float* __restrict__ w0, const float* __restrict__ b0,
    const float* __restrict__ w1, const float* __restrict__ b1,
    float* __restrict__ x1, __hip_bfloat16* __restrict__ h){
  __shared__ float sm[16];
  size_t row = blockIdx.x;
  int t = threadIdx.x;
  const float2* xr = (const float2*)(x + row * DIMV);
  float2 v = xr[t];
  float s = v.x + v.y;
  float sq = v.x * v.x + v.y * v.y;
  wave_reduce2(s, sq);
  int wid = t >> 6, lane = t & 63;
  if (lane == 0){ sm[wid] = s; sm[8 + wid] = sq; }
  __syncthreads();
  s  = sm[0] + sm[1] + sm[2] + sm[3];
  sq = sm[8] + sm[9] + sm[10] + sm[11];
  float mu = s * (1.f / DIMV);
  float var = sq * (1.f / DIMV) - mu * mu;
  float r = rsqrtf(var + 1e-5f);
  float2 ww = ((const float2*)w0)[t];
  float2 bb = ((const float2*)b0)[t];
  float2 y;
  y.x = (v.x - mu) * r * ww.x + bb.x;
  y.y = (v.y - mu) * r * ww.y + bb.y;
  ((float2*)(x1 + row * DIMV))[t] = y;
  float s2 = y.x + y.y, sq2 = y.x * y.x + y.y * y.y;
  wave_reduce2(s2, sq2);
  __syncthreads();
  if (lane == 0){ sm[wid] = s2; sm[8 + wid] = sq2; }
  __syncthreads();
  s2  = sm[0] + sm[1] + sm[2] + sm[3];
  sq2 = sm[8] + sm[9] + sm[10] + sm[11];
  float mu2 = s2 * (1.f / DIMV);
  float var2 = sq2 * (1.f / DIMV) - mu2 * mu2;
  float r2 = rsqrtf(var2 + 1e-5f);
  float2 w1v = ((const float2*)w1)[t];
  float2 b1v = ((const float2*)b1)[t];
  float hx = (y.x - mu2) * r2 * w1v.x + b1v.x;
  float hy = (y.y - mu2) * r2 * w1v.y + b1v.y;
  ushort2 hb; hb.x = f2bf(hx); hb.y = f2bf(hy);
  ((ushort2*)(h + row * DIMV))[t] = hb;
}

// Transpose fp32 W[K,N] -> bf16 Wt[N,K]
__global__ __launch_bounds__(256) void wtrans_kernel(const float* __restrict__ W,
    __hip_bfloat16* __restrict__ Wt, int K, int N){
  __shared__ float tile[32][33];
  int bn = blockIdx.x * 32;
  int bk = blockIdx.y * 32;
  int tx = threadIdx.x, ty = threadIdx.y;
  #pragma unroll
  for (int i = 0; i < 32; i += 8)
    tile[ty + i][tx] = W[(size_t)(bk + ty + i) * N + bn + tx];
  __syncthreads();
  #pragma unroll
  for (int i = 0; i < 32; i += 8)
    Wt[(size_t)(bn + ty + i) * K + bk + tx] = __float2bfloat16(tile[tx][ty + i]);
}

// Transpose V per (b,hh,p) slice: qkv V-part [n,64] -> vt[slice][d=64][n=1024]
__global__ __launch_bounds__(256) void vtrans_kernel(const __hip_bfloat16* __restrict__ qkvp,
                                                     ushort* __restrict__ vt){
  __shared__ ushort T[64 * 72];
  int sidx = blockIdx.x >> 4;          // b*64 + hh*8 + p
  int n0 = (blockIdx.x & 15) * 64;
  int b = sidx >> 6, hh = (sidx >> 3) & 7, p = sidx & 7;
  const ushort* vbase = (const ushort*)qkvp + (size_t)(b * PPV + p) * NSEQ * QKVW + 1024 + hh * DHEAD;
  int t = threadIdx.x;
  int r = t >> 2, c16 = (t & 3) * 16;
  const ushort* g = vbase + (size_t)(n0 + r) * QKVW + c16;
  *(short8*)&T[r * 72 + c16]     = *(const short8*)g;
  *(short8*)&T[r * 72 + c16 + 8] = *(const short8*)(g + 8);
  __syncthreads();
  int d = t >> 2, m16 = (t & 3) * 16;
  ushort* o = vt + (size_t)sidx * 65536 + (size_t)d * 1024 + n0 + m16;
  ushort tmp[16];
  #pragma unroll
  for (int j = 0; j < 16; j++) tmp[j] = T[(m16 + j) * 72 + d];
  *(short8*)o       = *(short8*)tmp;
  *(short8*)(o + 8) = *(short8*)(tmp + 8);
}

// MFMA bf16 GEMM (round-4 structure: BK=32, 16KB LDS) + fast_gelu + bf16 residual.
// 1D grid with XCD-aware swizzle: xcd = bid&7 owns M-strip [xcd*16, xcd*16+16) tiles;
// within strip, consecutive blocks sweep N (A-panel stays in that XCD's L2).
// C = A[M,K] @ Bt[N,K]^T (+bias)(gelu?)(+Rf fp32 | +Rb bf16) -> Cf fp32 / Cb bf16
__global__ __launch_bounds__(256) void gemm_mfma(
    const __hip_bfloat16* __restrict__ A,
    const __hip_bfloat16* __restrict__ Bt,
    const float* __restrict__ bias,
    const float* __restrict__ Rf,
    const __hip_bfloat16* __restrict__ Rb,
    float* __restrict__ Cf,
    __hip_bfloat16* __restrict__ Cb,
    int M, int N, int K, int gx, int dogelu)
{
  __shared__ __hip_bfloat16 As[128 * 32];
  __shared__ __hip_bfloat16 Bs[128 * 32];
  int tid = threadIdx.x;
  int w = tid >> 6, l = tid & 63;

  // XCD swizzle: gy = M/128 (=128), strip = 16 y-tiles per XCD
  int bid = blockIdx.x;
  int xcd = bid & 7, idx = bid >> 3;
  int xl = idx % gx, yl = idx / gx;
  size_t bm = (size_t)(xcd * 16 + yl) * 128;
  size_t bn = (size_t)xl * 128;
  int wm = (w & 1) * 64, wn = (w >> 1) * 64;

  int srow = w * 16 + (l >> 2);
  int scol = (l & 3) * 8;
  const __hip_bfloat16* Ag0 = A + (bm + srow) * K + scol;
  const __hip_bfloat16* Ag1 = A + (bm + 64 + srow) * K + scol;
  const __hip_bfloat16* Bg0 = Bt + (bn + srow) * K + scol;
  const __hip_bfloat16* Bg1 = Bt + (bn + 64 + srow) * K + scol;
  __hip_bfloat16* lA0 = &As[srow * 32 + scol];
  __hip_bfloat16* lA1 = &As[(64 + srow) * 32 + scol];
  __hip_bfloat16* lB0 = &Bs[srow * 32 + scol];
  __hip_bfloat16* lB1 = &Bs[(64 + srow) * 32 + scol];

  floatx4 acc[4][4] = {};
  int fm = l & 15;
  int fq = (l >> 4) * 8;

  for (int k0 = 0; k0 < K; k0 += 32){
    async_copy16(Ag0 + k0, lA0);
    async_copy16(Ag1 + k0, lA1);
    async_copy16(Bg0 + k0, lB0);
    async_copy16(Bg1 + k0, lB1);
    __syncthreads();
    short8 af[4], bf[4];
    #pragma unroll
    for (int i = 0; i < 4; i++){
      af[i] = *(const short8*)&As[(wm + i * 16 + fm) * 32 + fq];
      bf[i] = *(const short8*)&Bs[(wn + i * 16 + fm) * 32 + fq];
    }
    #pragma unroll
    for (int mi = 0; mi < 4; mi++)
      #pragma unroll
      for (int ni = 0; ni < 4; ni++)
        acc[mi][ni] = __builtin_amdgcn_mfma_f32_16x16x32_bf16(af[mi], bf[ni], acc[mi][ni], 0, 0, 0);
    __syncthreads();
  }

  // C/D layout: col = l&15, row = (l>>4)*4 + reg
  int rq = (l >> 4) * 4;
  #pragma unroll
  for (int ni = 0; ni < 4; ni++){
    size_t col = bn + wn + ni * 16 + fm;
    float bv = bias ? bias[col] : 0.f;
    #pragma unroll
    for (int mi = 0; mi < 4; mi++){
      #pragma unroll
      for (int r = 0; r < 4; r++){
        size_t row = bm + wm + mi * 16 + rq + r;
        float v = acc[mi][ni][r] + bv;
        if (dogelu) v = fast_gelu(v);
        size_t idx2 = row * N + col;
        if (Rf) v += Rf[idx2];
        if (Rb) v += bf2f(((const ushort*)Rb)[idx2]);
        if (Cf) Cf[idx2] = v;
        if (Cb) Cb[idx2] = __float2bfloat16(v);
      }
    }
  }
}

// MFMA flash attention (round-4 structure, unchanged).
#define SC2 0.18033688011112042f   // 0.125 * log2(e)
__global__ __launch_bounds__(256) void attn_mfma(const __hip_bfloat16* __restrict__ qkvp,
                                                 const ushort* __restrict__ vt,
                                                 __hip_bfloat16* __restrict__ outp){
  __shared__ ushort Ks[64 * 64];
  __shared__ ushort Vs[64 * 64];
  __shared__ ushort Ps[4][32 * 72];
  int tid = threadIdx.x;
  int w = tid >> 6, l = tid & 63;
  int r15 = l & 15, quad = l >> 4, fq = quad * 8;
  int slice = blockIdx.x & 127;
  int qc = blockIdx.x >> 7;
  int b = slice >> 6, hh = (slice >> 3) & 7, p = slice & 7;
  const ushort* base = (const ushort*)qkvp + (size_t)(b * PPV + p) * NSEQ * QKVW;
  const ushort* kb = base + 512 + hh * DHEAD;
  const ushort* vb = vt + (size_t)slice * 65536;

  int q0 = qc * 128 + w * 32;
  short8 qf[2][2];
  #pragma unroll
  for (int mi = 0; mi < 2; mi++)
    #pragma unroll
    for (int kk = 0; kk < 2; kk++)
      qf[mi][kk] = *(const short8*)(base + (size_t)(q0 + mi * 16 + r15) * QKVW + hh * DHEAD + kk * 32 + fq);

  floatx4 o[2][4] = {};
  floatx4 lacc[2] = {};
  short8 ones;
  #pragma unroll
  for (int j = 0; j < 8; j++) ones[j] = (short)0x3F80;

  int s0 = w * 64 + l, s1 = 256 + w * 64 + l;
  int row0 = s0 >> 3, row1 = s1 >> 3;
  int gc0 = (s0 & 7) ^ (row0 & 7), gc1 = (s1 & 7) ^ (row1 & 7);
  const ushort* kp0 = kb + (size_t)row0 * QKVW + gc0 * 8;
  const ushort* kp1 = kb + (size_t)row1 * QKVW + gc1 * 8;
  const ushort* vp0 = vb + (size_t)row0 * 1024 + gc0 * 8;
  const ushort* vp1 = vb + (size_t)row1 * 1024 + gc1 * 8;
  ushort* kd0 = &Ks[s0 * 8]; ushort* kd1 = &Ks[s1 * 8];
  ushort* vd0 = &Vs[s0 * 8]; ushort* vd1 = &Vs[s1 * 8];

  int sw = r15 & 7;

  for (int m0 = 0; m0 < NSEQ; m0 += 64){
    async_copy16(kp0 + (size_t)m0 * QKVW, kd0);
    async_copy16(kp1 + (size_t)m0 * QKVW, kd1);
    async_copy16(vp0 + m0, vd0);
    async_copy16(vp1 + m0, vd1);
    __syncthreads();

    floatx4 s[2][4] = {};
    #pragma unroll
    for (int ni = 0; ni < 4; ni++){
      int row = ni * 16 + r15;
      short8 kf0 = *(const short8*)&Ks[row * 64 + (quad ^ sw) * 8];
      short8 kf1 = *(const short8*)&Ks[row * 64 + ((4 + quad) ^ sw) * 8];
      #pragma unroll
      for (int mi = 0; mi < 2; mi++){
        s[mi][ni] = __builtin_amdgcn_mfma_f32_16x16x32_bf16(qf[mi][0], kf0, s[mi][ni], 0, 0, 0);
        s[mi][ni] = __builtin_amdgcn_mfma_f32_16x16x32_bf16(qf[mi][1], kf1, s[mi][ni], 0, 0, 0);
      }
    }

    #pragma unroll
    for (int mi = 0; mi < 2; mi++)
      #pragma unroll
      for (int ni = 0; ni < 4; ni++)
        #pragma unroll
        for (int r = 0; r < 4; r++){
          float pv = exp2f(s[mi][ni][r] * SC2);
          Ps[w][(mi * 16 + quad * 4 + r) * 72 + ni * 16 + r15] = f2bf(pv);
        }

    short8 pf[2][2];
    #pragma unroll
    for (int mi = 0; mi < 2; mi++)
      #pragma unroll
      for (int kk = 0; kk < 2; kk++)
        pf[mi][kk] = *(const short8*)&Ps[w][(mi * 16 + r15) * 72 + kk * 32 + fq];

    #pragma unroll
    for (int mi = 0; mi < 2; mi++)
      #pragma unroll
      for (int kk = 0; kk < 2; kk++)
        lacc[mi] = __builtin_amdgcn_mfma_f32_16x16x32_bf16(pf[mi][kk], ones, lacc[mi], 0, 0, 0);

    #pragma unroll
    for (int dj = 0; dj < 4; dj++){
      int d = dj * 16 + r15;
      #pragma unroll
      for (int kk = 0; kk < 2; kk++){
        short8 vf = *(const short8*)&Vs[d * 64 + (((kk * 4 + quad)) ^ sw) * 8];
        #pragma unroll
        for (int mi = 0; mi < 2; mi++)
          o[mi][dj] = __builtin_amdgcn_mfma_f32_16x16x32_bf16(pf[mi][kk], vf, o[mi][dj], 0, 0, 0);
      }
    }
    __syncthreads();
  }

  #pragma unroll
  for (int mi = 0; mi < 2; mi++){
    #pragma unroll
    for (int r = 0; r < 4; r++){
      float inv = 1.f / lacc[mi][r];
      size_t n = q0 + mi * 16 + quad * 4 + r;
      ushort* orow = (ushort*)outp + ((size_t)((b * HEADSV + hh) * NSEQ + n)) * DIMV + p * DHEAD;
      #pragma unroll
      for (int dj = 0; dj < 4; dj++)
        orow[dj * 16 + r15] = f2bf(o[mi][dj][r] * inv);
    }
  }
}

extern "C" void kernel_launch(void* const* d_in, const int* in_sizes, int n_in,
                              void* d_out, int out_size, void* d_ws, size_t ws_size,
                              hipStream_t stream){
  (void)in_sizes; (void)n_in; (void)out_size; (void)ws_size;
  const float* x    = (const float*)d_in[0];
  const float* lw0  = (const float*)d_in[1];
  const float* lb0  = (const float*)d_in[2];
  const float* lw1  = (const float*)d_in[3];
  const float* lb1  = (const float*)d_in[4];
  const float* wqkv = (const float*)d_in[5];
  const float* wo   = (const float*)d_in[6];
  const float* bo   = (const float*)d_in[7];
  const float* w1   = (const float*)d_in[8];
  const float* b1   = (const float*)d_in[9];
  const float* w2   = (const float*)d_in[10];
  const float* b2   = (const float*)d_in[11];
  float* out = (float*)d_out;
  char* ws = (char*)d_ws;
  const size_t MB = 1024 * 1024;

  // Workspace (peak 152 MB):
  // [0,32)    x1 fp32 (LN0 out; residual for wo-GEMM)
  // [32,64)   vt (16MB, dead after attn)
  // [64,80)   x2b bf16 (wo-GEMM out; residual for final GEMM)
  // [80,87)   transposed bf16 weights
  // [88,104)  h bf16 -> attnB bf16
  // [104,152) qkv bf16; tB spans [88,152) later
  float* x1            = (float*)(ws);
  ushort* vtbuf        = (ushort*)(ws + 32 * MB);
  __hip_bfloat16* x2b  = (__hip_bfloat16*)(ws + 64 * MB);
  __hip_bfloat16* wqkvT= (__hip_bfloat16*)(ws + 80 * MB);
  __hip_bfloat16* woT  = (__hip_bfloat16*)(ws + 82 * MB);
  __hip_bfloat16* w1T  = (__hip_bfloat16*)(ws + 83 * MB);
  __hip_bfloat16* w2T  = (__hip_bfloat16*)(ws + 85 * MB);
  __hip_bfloat16* hB   = (__hip_bfloat16*)(ws + 88 * MB);
  __hip_bfloat16* attnB= hB;
  __hip_bfloat16* qkvB = (__hip_bfloat16*)(ws + 104 * MB);
  __hip_bfloat16* tB   = (__hip_bfloat16*)(ws + 88 * MB);

  wtrans_kernel<<<dim3(48, 16), dim3(32, 8), 0, stream>>>(wqkv, wqkvT, 512, 1536);
  wtrans_kernel<<<dim3(16, 16), dim3(32, 8), 0, stream>>>(wo,   woT,   512, 512);
  wtrans_kernel<<<dim3(64, 16), dim3(32, 8), 0, stream>>>(w1,   w1T,   512, 2048);
  wtrans_kernel<<<dim3(16, 64), dim3(32, 8), 0, stream>>>(w2,   w2T,   2048, 512);

  ln2_kernel<<<NTOK, 256, 0, stream>>>(x, lw0, lb0, lw1, lb1, x1, hB);

  // qkv = h @ w_qkv -> bf16   (grid = gx*gy, gx = N/128, gy = 128)
  gemm_mfma<<<(QKVW / 128) * 128, 256, 0, stream>>>(
      hB, wqkvT, nullptr, nullptr, nullptr, nullptr, qkvB,
      NTOK, QKVW, DIMV, QKVW / 128, 0);

  vtrans_kernel<<<2048, 256, 0, stream>>>(qkvB, vtbuf);

  attn_mfma<<<1024, 256, 0, stream>>>(qkvB, vtbuf, attnB);

  // x2b = attn @ w_o + b_o + x1 (fp32 residual) -> bf16 only
  gemm_mfma<<<(DIMV / 128) * 128, 256, 0, stream>>>(
      attnB, woT, bo, x1, nullptr, nullptr, x2b,
      NTOK, DIMV, DIMV, DIMV / 128, 0);

  // t = gelu_fast(x2b @ w1 + b1) -> bf16
  gemm_mfma<<<(HIDV / 128) * 128, 256, 0, stream>>>(
      x2b, w1T, b1, nullptr, nullptr, nullptr, tB,
      NTOK, HIDV, DIMV, HIDV / 128, 1);

  // out = t @ w2 + b2 + x2b (bf16 residual) -> fp32
  gemm_mfma<<<(DIMV / 128) * 128, 256, 0, stream>>>(
      tB, w2T, b2, nullptr, x2b, out, nullptr,
      NTOK, DIMV, HIDV, DIMV / 128, 0);
}

// Round 7
// 457.321 us; speedup vs baseline: 1.3200x; 1.0097x over previous
//
#include <hip/hip_runtime.h>
#include <hip/hip_bf16.h>
#include <math.h>

#define DIMV 512
#define NTOK 16384   // B*P*N = 2*8*1024
#define NSEQ 1024
#define HEADSV 8
#define PPV 8
#define DHEAD 64
#define QKVW 1536
#define HIDV 2048

typedef unsigned short ushort;
typedef __attribute__((ext_vector_type(8))) short short8;
typedef __attribute__((ext_vector_type(8))) unsigned short ushort8;
typedef __attribute__((ext_vector_type(4))) unsigned short ushortx4;
typedef __attribute__((ext_vector_type(4))) float floatx4;

__device__ __forceinline__ float bf2f(ushort u){
  union { unsigned int i; float f; } c; c.i = ((unsigned int)u) << 16; return c.f;
}
__device__ __forceinline__ ushort f2bf(float f){
  __hip_bfloat16 h = __float2bfloat16(f);
  ushort u; __builtin_memcpy(&u, &h, 2); return u;
}
__device__ __forceinline__ void async_copy16(const void* gptr, void* lptr){
  __builtin_amdgcn_global_load_lds((const __attribute__((address_space(1))) void*)gptr,
                                   (__attribute__((address_space(3))) void*)lptr, 16, 0, 0);
}
// tanh-form GELU via one v_exp_f32: x * sigmoid(1.5957691x + 0.0713548x^3)
__device__ __forceinline__ float fast_gelu(float x){
  float u = x * (2.3022084f + 0.1029435f * x * x);   // (2u)*log2(e)
  return x * __builtin_amdgcn_rcpf(1.f + exp2f(-u));
}

__device__ __forceinline__ void wave_reduce2(float& a, float& b){
  #pragma unroll
  for (int off = 32; off > 0; off >>= 1){
    a += __shfl_down(a, off, 64);
    b += __shfl_down(b, off, 64);
  }
}

// One block per token row: x -> LN0 -> x1 (bf16), LN1 -> h (bf16)
__global__ __launch_bounds__(256) void ln2_kernel(const float* __restrict__ x,
    const float* __restrict__ w0, const float* __restrict__ b0,
    const float* __restrict__ w1, const float* __restrict__ b1,
    __hip_bfloat16* __restrict__ x1, __hip_bfloat16* __restrict__ h){
  __shared__ float sm[16];
  size_t row = blockIdx.x;
  int t = threadIdx.x;
  const float2* xr = (const float2*)(x + row * DIMV);
  float2 v = xr[t];
  float s = v.x + v.y;
  float sq = v.x * v.x + v.y * v.y;
  wave_reduce2(s, sq);
  int wid = t >> 6, lane = t & 63;
  if (lane == 0){ sm[wid] = s; sm[8 + wid] = sq; }
  __syncthreads();
  s  = sm[0] + sm[1] + sm[2] + sm[3];
  sq = sm[8] + sm[9] + sm[10] + sm[11];
  float mu = s * (1.f / DIMV);
  float var = sq * (1.f / DIMV) - mu * mu;
  float r = rsqrtf(var + 1e-5f);
  float2 ww = ((const float2*)w0)[t];
  float2 bb = ((const float2*)b0)[t];
  float2 y;
  y.x = (v.x - mu) * r * ww.x + bb.x;
  y.y = (v.y - mu) * r * ww.y + bb.y;
  ushort2 xb; xb.x = f2bf(y.x); xb.y = f2bf(y.y);
  ((ushort2*)(x1 + row * DIMV))[t] = xb;
  float s2 = y.x + y.y, sq2 = y.x * y.x + y.y * y.y;
  wave_reduce2(s2, sq2);
  __syncthreads();
  if (lane == 0){ sm[wid] = s2; sm[8 + wid] = sq2; }
  __syncthreads();
  s2  = sm[0] + sm[1] + sm[2] + sm[3];
  sq2 = sm[8] + sm[9] + sm[10] + sm[11];
  float mu2 = s2 * (1.f / DIMV);
  float var2 = sq2 * (1.f / DIMV) - mu2 * mu2;
  float r2 = rsqrtf(var2 + 1e-5f);
  float2 w1v = ((const float2*)w1)[t];
  float2 b1v = ((const float2*)b1)[t];
  float hx = (y.x - mu2) * r2 * w1v.x + b1v.x;
  float hy = (y.y - mu2) * r2 * w1v.y + b1v.y;
  ushort2 hb; hb.x = f2bf(hx); hb.y = f2bf(hy);
  ((ushort2*)(h + row * DIMV))[t] = hb;
}

// Transpose fp32 W[K,N] -> bf16 Wt[N,K]
__global__ __launch_bounds__(256) void wtrans_kernel(const float* __restrict__ W,
    __hip_bfloat16* __restrict__ Wt, int K, int N){
  __shared__ float tile[32][33];
  int bn = blockIdx.x * 32;
  int bk = blockIdx.y * 32;
  int tx = threadIdx.x, ty = threadIdx.y;
  #pragma unroll
  for (int i = 0; i < 32; i += 8)
    tile[ty + i][tx] = W[(size_t)(bk + ty + i) * N + bn + tx];
  __syncthreads();
  #pragma unroll
  for (int i = 0; i < 32; i += 8)
    Wt[(size_t)(bn + ty + i) * K + bk + tx] = __float2bfloat16(tile[tx][ty + i]);
}

// Transpose V per (b,hh,p) slice: qkv V-part [n,64] -> vt[slice][d=64][n=1024]
__global__ __launch_bounds__(256) void vtrans_kernel(const __hip_bfloat16* __restrict__ qkvp,
                                                     ushort* __restrict__ vt){
  __shared__ ushort T[64 * 72];
  int sidx = blockIdx.x >> 4;          // b*64 + hh*8 + p
  int n0 = (blockIdx.x & 15) * 64;
  int b = sidx >> 6, hh = (sidx >> 3) & 7, p = sidx & 7;
  const ushort* vbase = (const ushort*)qkvp + (size_t)(b * PPV + p) * NSEQ * QKVW + 1024 + hh * DHEAD;
  int t = threadIdx.x;
  int r = t >> 2, c16 = (t & 3) * 16;
  const ushort* g = vbase + (size_t)(n0 + r) * QKVW + c16;
  *(short8*)&T[r * 72 + c16]     = *(const short8*)g;
  *(short8*)&T[r * 72 + c16 + 8] = *(const short8*)(g + 8);
  __syncthreads();
  int d = t >> 2, m16 = (t & 3) * 16;
  ushort* o = vt + (size_t)sidx * 65536 + (size_t)d * 1024 + n0 + m16;
  ushort tmp[16];
  #pragma unroll
  for (int j = 0; j < 16; j++) tmp[j] = T[(m16 + j) * 72 + d];
  *(short8*)o       = *(short8*)tmp;
  *(short8*)(o + 8) = *(short8*)(tmp + 8);
}

// MFMA bf16 GEMM: BK=32, 128x128 tile, XCD-swizzled 1D grid.
// C = A[M,K] @ Bt[N,K]^T (+bias)(gelu?)(+Rb bf16) -> Cf fp32 (scattered) or Cb bf16
// (LDS-staged coalesced epilogue).
__global__ __launch_bounds__(256) void gemm_mfma(
    const __hip_bfloat16* __restrict__ A,
    const __hip_bfloat16* __restrict__ Bt,
    const float* __restrict__ bias,
    const __hip_bfloat16* __restrict__ Rb,
    float* __restrict__ Cf,
    __hip_bfloat16* __restrict__ Cb,
    int M, int N, int K, int gx, int dogelu)
{
  __shared__ ushort SM[16896];   // 33792 B: K-loop uses [0,8192) As + Bs; epilogue stages 128x132
  ushort* Asm = SM;              // 128*32
  ushort* Bsm = SM + 4096;       // 128*32
  int tid = threadIdx.x;
  int w = tid >> 6, l = tid & 63;

  // XCD swizzle: xcd = bid&7 owns M-strip of 16 y-tiles; sweep N within strip
  int bid = blockIdx.x;
  int xcd = bid & 7, idx = bid >> 3;
  int xl = idx % gx, yl = idx / gx;
  size_t bm = (size_t)(xcd * 16 + yl) * 128;
  size_t bn = (size_t)xl * 128;
  int wm = (w & 1) * 64, wn = (w >> 1) * 64;

  int srow = w * 16 + (l >> 2);
  int scol = (l & 3) * 8;
  const ushort* Ag0 = (const ushort*)A + (bm + srow) * K + scol;
  const ushort* Ag1 = (const ushort*)A + (bm + 64 + srow) * K + scol;
  const ushort* Bg0 = (const ushort*)Bt + (bn + srow) * K + scol;
  const ushort* Bg1 = (const ushort*)Bt + (bn + 64 + srow) * K + scol;
  ushort* lA0 = &Asm[srow * 32 + scol];
  ushort* lA1 = &Asm[(64 + srow) * 32 + scol];
  ushort* lB0 = &Bsm[srow * 32 + scol];
  ushort* lB1 = &Bsm[(64 + srow) * 32 + scol];

  floatx4 acc[4][4] = {};
  int fm = l & 15;
  int quad = l >> 4;
  int fq = quad * 8;

  for (int k0 = 0; k0 < K; k0 += 32){
    async_copy16(Ag0 + k0, lA0);
    async_copy16(Ag1 + k0, lA1);
    async_copy16(Bg0 + k0, lB0);
    async_copy16(Bg1 + k0, lB1);
    __syncthreads();
    short8 af[4], bf[4];
    #pragma unroll
    for (int i = 0; i < 4; i++){
      af[i] = *(const short8*)&Asm[(wm + i * 16 + fm) * 32 + fq];
      bf[i] = *(const short8*)&Bsm[(wn + i * 16 + fm) * 32 + fq];
    }
    #pragma unroll
    for (int mi = 0; mi < 4; mi++)
      #pragma unroll
      for (int ni = 0; ni < 4; ni++)
        acc[mi][ni] = __builtin_amdgcn_mfma_f32_16x16x32_bf16(af[mi], bf[ni], acc[mi][ni], 0, 0, 0);
    __syncthreads();
  }

  // C/D layout: col = l&15, row = quad*4 + reg
  int rq = quad * 4;
  if (Cb){
    // ---- bf16 out: stage tile row-major (stride 132) then coalesced 16B stores ----
    #pragma unroll
    for (int ni = 0; ni < 4; ni++){
      int col = wn + ni * 16 + fm;
      float bv = bias ? bias[bn + col] : 0.f;
      #pragma unroll
      for (int mi = 0; mi < 4; mi++){
        int row = wm + mi * 16 + rq;
        #pragma unroll
        for (int r = 0; r < 4; r++){
          float v = acc[mi][ni][r] + bv;
          if (dogelu) v = fast_gelu(v);
          SM[(row + r) * 132 + col] = f2bf(v);
        }
      }
    }
    __syncthreads();
    int row = tid >> 1, ch = (tid & 1) * 64;
    const ushort* rs = &SM[row * 132 + ch];
    size_t gbase = (bm + row) * N + bn + ch;
    #pragma unroll
    for (int j = 0; j < 8; j++){
      ushortx4 lo = *(const ushortx4*)(rs + j * 8);
      ushortx4 hi = *(const ushortx4*)(rs + j * 8 + 4);
      ushort8 v8;
      v8[0]=lo[0]; v8[1]=lo[1]; v8[2]=lo[2]; v8[3]=lo[3];
      v8[4]=hi[0]; v8[5]=hi[1]; v8[6]=hi[2]; v8[7]=hi[3];
      if (Rb){
        ushort8 rb = *(const ushort8*)((const ushort*)Rb + gbase + j * 8);
        #pragma unroll
        for (int e = 0; e < 8; e++) v8[e] = f2bf(bf2f(v8[e]) + bf2f(rb[e]));
      }
      *(ushort8*)((ushort*)Cb + gbase + j * 8) = v8;
    }
  } else {
    // ---- fp32 out (final GEMM): scattered store path ----
    #pragma unroll
    for (int ni = 0; ni < 4; ni++){
      size_t col = bn + wn + ni * 16 + fm;
      float bv = bias ? bias[col] : 0.f;
      #pragma unroll
      for (int mi = 0; mi < 4; mi++){
        #pragma unroll
        for (int r = 0; r < 4; r++){
          size_t row = bm + wm + mi * 16 + rq + r;
          float v = acc[mi][ni][r] + bv;
          if (dogelu) v = fast_gelu(v);
          size_t idx2 = row * N + col;
          if (Rb) v += bf2f(((const ushort*)Rb)[idx2]);
          Cf[idx2] = v;
        }
      }
    }
  }
}

// MFMA flash attention (round-4 structure, unchanged).
#define SC2 0.18033688011112042f   // 0.125 * log2(e)
__global__ __launch_bounds__(256) void attn_mfma(const __hip_bfloat16* __restrict__ qkvp,
                                                 const ushort* __restrict__ vt,
                                                 __hip_bfloat16* __restrict__ outp){
  __shared__ ushort Ks[64 * 64];
  __shared__ ushort Vs[64 * 64];
  __shared__ ushort Ps[4][32 * 72];
  int tid = threadIdx.x;
  int w = tid >> 6, l = tid & 63;
  int r15 = l & 15, quad = l >> 4, fq = quad * 8;
  int slice = blockIdx.x & 127;
  int qc = blockIdx.x >> 7;
  int b = slice >> 6, hh = (slice >> 3) & 7, p = slice & 7;
  const ushort* base = (const ushort*)qkvp + (size_t)(b * PPV + p) * NSEQ * QKVW;
  const ushort* kb = base + 512 + hh * DHEAD;
  const ushort* vb = vt + (size_t)slice * 65536;

  int q0 = qc * 128 + w * 32;
  short8 qf[2][2];
  #pragma unroll
  for (int mi = 0; mi < 2; mi++)
    #pragma unroll
    for (int kk = 0; kk < 2; kk++)
      qf[mi][kk] = *(const short8*)(base + (size_t)(q0 + mi * 16 + r15) * QKVW + hh * DHEAD + kk * 32 + fq);

  floatx4 o[2][4] = {};
  floatx4 lacc[2] = {};
  short8 ones;
  #pragma unroll
  for (int j = 0; j < 8; j++) ones[j] = (short)0x3F80;

  int s0 = w * 64 + l, s1 = 256 + w * 64 + l;
  int row0 = s0 >> 3, row1 = s1 >> 3;
  int gc0 = (s0 & 7) ^ (row0 & 7), gc1 = (s1 & 7) ^ (row1 & 7);
  const ushort* kp0 = kb + (size_t)row0 * QKVW + gc0 * 8;
  const ushort* kp1 = kb + (size_t)row1 * QKVW + gc1 * 8;
  const ushort* vp0 = vb + (size_t)row0 * 1024 + gc0 * 8;
  const ushort* vp1 = vb + (size_t)row1 * 1024 + gc1 * 8;
  ushort* kd0 = &Ks[s0 * 8]; ushort* kd1 = &Ks[s1 * 8];
  ushort* vd0 = &Vs[s0 * 8]; ushort* vd1 = &Vs[s1 * 8];

  int sw = r15 & 7;

  for (int m0 = 0; m0 < NSEQ; m0 += 64){
    async_copy16(kp0 + (size_t)m0 * QKVW, kd0);
    async_copy16(kp1 + (size_t)m0 * QKVW, kd1);
    async_copy16(vp0 + m0, vd0);
    async_copy16(vp1 + m0, vd1);
    __syncthreads();

    floatx4 s[2][4] = {};
    #pragma unroll
    for (int ni = 0; ni < 4; ni++){
      int row = ni * 16 + r15;
      short8 kf0 = *(const short8*)&Ks[row * 64 + (quad ^ sw) * 8];
      short8 kf1 = *(const short8*)&Ks[row * 64 + ((4 + quad) ^ sw) * 8];
      #pragma unroll
      for (int mi = 0; mi < 2; mi++){
        s[mi][ni] = __builtin_amdgcn_mfma_f32_16x16x32_bf16(qf[mi][0], kf0, s[mi][ni], 0, 0, 0);
        s[mi][ni] = __builtin_amdgcn_mfma_f32_16x16x32_bf16(qf[mi][1], kf1, s[mi][ni], 0, 0, 0);
      }
    }

    #pragma unroll
    for (int mi = 0; mi < 2; mi++)
      #pragma unroll
      for (int ni = 0; ni < 4; ni++)
        #pragma unroll
        for (int r = 0; r < 4; r++){
          float pv = exp2f(s[mi][ni][r] * SC2);
          Ps[w][(mi * 16 + quad * 4 + r) * 72 + ni * 16 + r15] = f2bf(pv);
        }

    short8 pf[2][2];
    #pragma unroll
    for (int mi = 0; mi < 2; mi++)
      #pragma unroll
      for (int kk = 0; kk < 2; kk++)
        pf[mi][kk] = *(const short8*)&Ps[w][(mi * 16 + r15) * 72 + kk * 32 + fq];

    #pragma unroll
    for (int mi = 0; mi < 2; mi++)
      #pragma unroll
      for (int kk = 0; kk < 2; kk++)
        lacc[mi] = __builtin_amdgcn_mfma_f32_16x16x32_bf16(pf[mi][kk], ones, lacc[mi], 0, 0, 0);

    #pragma unroll
    for (int dj = 0; dj < 4; dj++){
      int d = dj * 16 + r15;
      #pragma unroll
      for (int kk = 0; kk < 2; kk++){
        short8 vf = *(const short8*)&Vs[d * 64 + (((kk * 4 + quad)) ^ sw) * 8];
        #pragma unroll
        for (int mi = 0; mi < 2; mi++)
          o[mi][dj] = __builtin_amdgcn_mfma_f32_16x16x32_bf16(pf[mi][kk], vf, o[mi][dj], 0, 0, 0);
      }
    }
    __syncthreads();
  }

  #pragma unroll
  for (int mi = 0; mi < 2; mi++){
    #pragma unroll
    for (int r = 0; r < 4; r++){
      float inv = 1.f / lacc[mi][r];
      size_t n = q0 + mi * 16 + quad * 4 + r;
      ushort* orow = (ushort*)outp + ((size_t)((b * HEADSV + hh) * NSEQ + n)) * DIMV + p * DHEAD;
      #pragma unroll
      for (int dj = 0; dj < 4; dj++)
        orow[dj * 16 + r15] = f2bf(o[mi][dj][r] * inv);
    }
  }
}

extern "C" void kernel_launch(void* const* d_in, const int* in_sizes, int n_in,
                              void* d_out, int out_size, void* d_ws, size_t ws_size,
                              hipStream_t stream){
  (void)in_sizes; (void)n_in; (void)out_size; (void)ws_size;
  const float* x    = (const float*)d_in[0];
  const float* lw0  = (const float*)d_in[1];
  const float* lb0  = (const float*)d_in[2];
  const float* lw1  = (const float*)d_in[3];
  const float* lb1  = (const float*)d_in[4];
  const float* wqkv = (const float*)d_in[5];
  const float* wo   = (const float*)d_in[6];
  const float* bo   = (const float*)d_in[7];
  const float* w1   = (const float*)d_in[8];
  const float* b1   = (const float*)d_in[9];
  const float* w2   = (const float*)d_in[10];
  const float* b2   = (const float*)d_in[11];
  float* out = (float*)d_out;
  char* ws = (char*)d_ws;
  const size_t MB = 1024 * 1024;

  // Workspace (peak 152 MB):
  // [0,16)    x1b bf16 (LN0 out; residual for wo-GEMM)
  // [32,64)   vt (16MB, dead after attn)
  // [64,80)   x2b bf16 (wo-GEMM out; residual for final GEMM)
  // [80,87)   transposed bf16 weights
  // [88,104)  h bf16 -> attnB bf16
  // [104,152) qkv bf16; tB spans [88,152) later
  __hip_bfloat16* x1b  = (__hip_bfloat16*)(ws);
  ushort* vtbuf        = (ushort*)(ws + 32 * MB);
  __hip_bfloat16* x2b  = (__hip_bfloat16*)(ws + 64 * MB);
  __hip_bfloat16* wqkvT= (__hip_bfloat16*)(ws + 80 * MB);
  __hip_bfloat16* woT  = (__hip_bfloat16*)(ws + 82 * MB);
  __hip_bfloat16* w1T  = (__hip_bfloat16*)(ws + 83 * MB);
  __hip_bfloat16* w2T  = (__hip_bfloat16*)(ws + 85 * MB);
  __hip_bfloat16* hB   = (__hip_bfloat16*)(ws + 88 * MB);
  __hip_bfloat16* attnB= hB;
  __hip_bfloat16* qkvB = (__hip_bfloat16*)(ws + 104 * MB);
  __hip_bfloat16* tB   = (__hip_bfloat16*)(ws + 88 * MB);

  wtrans_kernel<<<dim3(48, 16), dim3(32, 8), 0, stream>>>(wqkv, wqkvT, 512, 1536);
  wtrans_kernel<<<dim3(16, 16), dim3(32, 8), 0, stream>>>(wo,   woT,   512, 512);
  wtrans_kernel<<<dim3(64, 16), dim3(32, 8), 0, stream>>>(w1,   w1T,   512, 2048);
  wtrans_kernel<<<dim3(16, 64), dim3(32, 8), 0, stream>>>(w2,   w2T,   2048, 512);

  ln2_kernel<<<NTOK, 256, 0, stream>>>(x, lw0, lb0, lw1, lb1, x1b, hB);

  // qkv = h @ w_qkv -> bf16
  gemm_mfma<<<(QKVW / 128) * 128, 256, 0, stream>>>(
      hB, wqkvT, nullptr, nullptr, nullptr, qkvB,
      NTOK, QKVW, DIMV, QKVW / 128, 0);

  vtrans_kernel<<<2048, 256, 0, stream>>>(qkvB, vtbuf);

  attn_mfma<<<1024, 256, 0, stream>>>(qkvB, vtbuf, attnB);

  // x2b = attn @ w_o + b_o + x1b (bf16 residual) -> bf16
  gemm_mfma<<<(DIMV / 128) * 128, 256, 0, stream>>>(
      attnB, woT, bo, x1b, nullptr, x2b,
      NTOK, DIMV, DIMV, DIMV / 128, 0);

  // t = gelu_fast(x2b @ w1 + b1) -> bf16
  gemm_mfma<<<(HIDV / 128) * 128, 256, 0, stream>>>(
      x2b, w1T, b1, nullptr, nullptr, tB,
      NTOK, HIDV, DIMV, HIDV / 128, 1);

  // out = t @ w2 + b2 + x2b (bf16 residual) -> fp32
  gemm_mfma<<<(DIMV / 128) * 128, 256, 0, stream>>>(
      tB, w2T, b2, x2b, out, nullptr,
      NTOK, DIMV, HIDV, DIMV / 128, 0);
}

// Round 8
// 421.741 us; speedup vs baseline: 1.4314x; 1.0844x over previous
//
#include <hip/hip_runtime.h>
#include <hip/hip_bf16.h>
#include <math.h>

#define DIMV 512
#define NTOK 16384   // B*P*N = 2*8*1024
#define NSEQ 1024
#define HEADSV 8
#define PPV 8
#define DHEAD 64
#define QKVW 1536
#define HIDV 2048

typedef unsigned short ushort;
typedef __attribute__((ext_vector_type(8))) short short8;
typedef __attribute__((ext_vector_type(8))) unsigned short ushort8;
typedef __attribute__((ext_vector_type(4))) unsigned short ushortx4;
typedef __attribute__((ext_vector_type(4))) float floatx4;

__device__ __forceinline__ float bf2f(ushort u){
  union { unsigned int i; float f; } c; c.i = ((unsigned int)u) << 16; return c.f;
}
__device__ __forceinline__ ushort f2bf(float f){
  __hip_bfloat16 h = __float2bfloat16(f);
  ushort u; __builtin_memcpy(&u, &h, 2); return u;
}
__device__ __forceinline__ void async_copy16(const void* gptr, void* lptr){
  __builtin_amdgcn_global_load_lds((const __attribute__((address_space(1))) void*)gptr,
                                   (__attribute__((address_space(3))) void*)lptr, 16, 0, 0);
}
// tanh-form GELU via one v_exp_f32: x * sigmoid(1.5957691x + 0.0713548x^3)
__device__ __forceinline__ float fast_gelu(float x){
  float u = x * (2.3022084f + 0.1029435f * x * x);   // (2u)*log2(e)
  return x * __builtin_amdgcn_rcpf(1.f + exp2f(-u));
}

__device__ __forceinline__ void wave_reduce2(float& a, float& b){
  #pragma unroll
  for (int off = 32; off > 0; off >>= 1){
    a += __shfl_down(a, off, 64);
    b += __shfl_down(b, off, 64);
  }
}

// ---- fused prep kernel: LN (blocks [0,16384)) + 4 weight transposes ----
// wtrans ranges: wqkv 768, wo 256, w1 1024, w2 1024  (total 3072)
__device__ __forceinline__ void wtrans_body(const float* __restrict__ W,
    __hip_bfloat16* __restrict__ Wt, int K, int N, int bx, int by, int t,
    float* tile /* 32*33 */){
  int bn = bx * 32, bk = by * 32;
  int tx = t & 31, ty = t >> 5;
  #pragma unroll
  for (int i = 0; i < 32; i += 8)
    tile[(ty + i) * 33 + tx] = W[(size_t)(bk + ty + i) * N + bn + tx];
  __syncthreads();
  #pragma unroll
  for (int i = 0; i < 32; i += 8)
    Wt[(size_t)(bn + ty + i) * K + bk + tx] = __float2bfloat16(tile[tx * 33 + ty + i]);
}

__global__ __launch_bounds__(256) void prep_kernel(const float* __restrict__ x,
    const float* __restrict__ w0, const float* __restrict__ b0,
    const float* __restrict__ w1ln, const float* __restrict__ b1ln,
    __hip_bfloat16* __restrict__ x1, __hip_bfloat16* __restrict__ h,
    const float* __restrict__ wqkv, __hip_bfloat16* __restrict__ wqkvT,
    const float* __restrict__ wo,   __hip_bfloat16* __restrict__ woT,
    const float* __restrict__ w1,   __hip_bfloat16* __restrict__ w1T,
    const float* __restrict__ w2,   __hip_bfloat16* __restrict__ w2T){
  __shared__ float smem[32 * 33];
  int bid = blockIdx.x;
  int t = threadIdx.x;
  if (bid >= NTOK){
    int r = bid - NTOK;
    if (r < 768)        wtrans_body(wqkv, wqkvT, 512, 1536, r % 48, r / 48, t, smem);
    else if (r < 1024){ r -= 768;  wtrans_body(wo, woT, 512, 512,  r % 16, r / 16, t, smem); }
    else if (r < 2048){ r -= 1024; wtrans_body(w1, w1T, 512, 2048, r % 64, r / 64, t, smem); }
    else             { r -= 2048; wtrans_body(w2, w2T, 2048, 512, r % 16, r / 16, t, smem); }
    return;
  }
  // ---- double LN ----
  float* sm = smem;
  size_t row = bid;
  const float2* xr = (const float2*)(x + row * DIMV);
  float2 v = xr[t];
  float s = v.x + v.y;
  float sq = v.x * v.x + v.y * v.y;
  wave_reduce2(s, sq);
  int wid = t >> 6, lane = t & 63;
  if (lane == 0){ sm[wid] = s; sm[8 + wid] = sq; }
  __syncthreads();
  s  = sm[0] + sm[1] + sm[2] + sm[3];
  sq = sm[8] + sm[9] + sm[10] + sm[11];
  float mu = s * (1.f / DIMV);
  float var = sq * (1.f / DIMV) - mu * mu;
  float r = rsqrtf(var + 1e-5f);
  float2 ww = ((const float2*)w0)[t];
  float2 bb = ((const float2*)b0)[t];
  float2 y;
  y.x = (v.x - mu) * r * ww.x + bb.x;
  y.y = (v.y - mu) * r * ww.y + bb.y;
  ushort2 xb; xb.x = f2bf(y.x); xb.y = f2bf(y.y);
  ((ushort2*)(x1 + row * DIMV))[t] = xb;
  float s2 = y.x + y.y, sq2 = y.x * y.x + y.y * y.y;
  wave_reduce2(s2, sq2);
  __syncthreads();
  if (lane == 0){ sm[wid] = s2; sm[8 + wid] = sq2; }
  __syncthreads();
  s2  = sm[0] + sm[1] + sm[2] + sm[3];
  sq2 = sm[8] + sm[9] + sm[10] + sm[11];
  float mu2 = s2 * (1.f / DIMV);
  float var2 = sq2 * (1.f / DIMV) - mu2 * mu2;
  float r2 = rsqrtf(var2 + 1e-5f);
  float2 w1v = ((const float2*)w1ln)[t];
  float2 b1v = ((const float2*)b1ln)[t];
  float hx = (y.x - mu2) * r2 * w1v.x + b1v.x;
  float hy = (y.y - mu2) * r2 * w1v.y + b1v.y;
  ushort2 hb; hb.x = f2bf(hx); hb.y = f2bf(hy);
  ((ushort2*)(h + row * DIMV))[t] = hb;
}

// MFMA bf16 GEMM: BK=32, 128x128 tile, XCD-swizzled 1D grid (round-6 structure).
// C = A[M,K] @ Bt[N,K]^T (+bias)(gelu?)(+Rb bf16) -> Cf fp32 or Cb bf16.
// If vt != null (qkv GEMM): blocks with bn >= 1024 (V columns) write TRANSPOSED
// into vt[slice][d][n] and skip the normal store.
__global__ __launch_bounds__(256) void gemm_mfma(
    const __hip_bfloat16* __restrict__ A,
    const __hip_bfloat16* __restrict__ Bt,
    const float* __restrict__ bias,
    const __hip_bfloat16* __restrict__ Rb,
    float* __restrict__ Cf,
    __hip_bfloat16* __restrict__ Cb,
    ushort* __restrict__ vt,
    int M, int N, int K, int gx, int dogelu)
{
  __shared__ __hip_bfloat16 As[128 * 32];
  __shared__ __hip_bfloat16 Bs[128 * 32];
  int tid = threadIdx.x;
  int w = tid >> 6, l = tid & 63;

  // XCD swizzle: xcd = bid&7 owns M-strip of 16 y-tiles; sweep N within strip
  int bid = blockIdx.x;
  int xcd = bid & 7, idx = bid >> 3;
  int xl = idx % gx, yl = idx / gx;
  size_t bm = (size_t)(xcd * 16 + yl) * 128;
  size_t bn = (size_t)xl * 128;
  int wm = (w & 1) * 64, wn = (w >> 1) * 64;

  int srow = w * 16 + (l >> 2);
  int scol = (l & 3) * 8;
  const __hip_bfloat16* Ag0 = A + (bm + srow) * K + scol;
  const __hip_bfloat16* Ag1 = A + (bm + 64 + srow) * K + scol;
  const __hip_bfloat16* Bg0 = Bt + (bn + srow) * K + scol;
  const __hip_bfloat16* Bg1 = Bt + (bn + 64 + srow) * K + scol;
  __hip_bfloat16* lA0 = &As[srow * 32 + scol];
  __hip_bfloat16* lA1 = &As[(64 + srow) * 32 + scol];
  __hip_bfloat16* lB0 = &Bs[srow * 32 + scol];
  __hip_bfloat16* lB1 = &Bs[(64 + srow) * 32 + scol];

  floatx4 acc[4][4] = {};
  int fm = l & 15;
  int quad = l >> 4;
  int fq = quad * 8;

  for (int k0 = 0; k0 < K; k0 += 32){
    async_copy16(Ag0 + k0, lA0);
    async_copy16(Ag1 + k0, lA1);
    async_copy16(Bg0 + k0, lB0);
    async_copy16(Bg1 + k0, lB1);
    __syncthreads();
    short8 af[4], bf[4];
    #pragma unroll
    for (int i = 0; i < 4; i++){
      af[i] = *(const short8*)&As[(wm + i * 16 + fm) * 32 + fq];
      bf[i] = *(const short8*)&Bs[(wn + i * 16 + fm) * 32 + fq];
    }
    #pragma unroll
    for (int mi = 0; mi < 4; mi++)
      #pragma unroll
      for (int ni = 0; ni < 4; ni++)
        acc[mi][ni] = __builtin_amdgcn_mfma_f32_16x16x32_bf16(af[mi], bf[ni], acc[mi][ni], 0, 0, 0);
    __syncthreads();
  }

  // C/D layout: col = l&15, row = quad*4 + reg
  int rq = quad * 4;
  if (vt && bn >= 1024){
    // ---- qkv V-columns: write transposed into vt[slice][d][n] ----
    int b = (int)(bm >> 13), p = (int)((bm >> 10) & 7);
    int n0 = (int)(bm & 1023) + wm + rq;
    int cbase = (int)bn + wn - 1024;
    #pragma unroll
    for (int ni = 0; ni < 4; ni++){
      int cc = cbase + ni * 16 + fm;
      int hh = cc >> 6, dd = cc & 63;
      ushort* vdst = vt + ((size_t)((b * 8 + hh) * 8 + p)) * 65536 + (size_t)dd * 1024;
      #pragma unroll
      for (int mi = 0; mi < 4; mi++){
        ushortx4 v4;
        v4[0] = f2bf(acc[mi][ni][0]); v4[1] = f2bf(acc[mi][ni][1]);
        v4[2] = f2bf(acc[mi][ni][2]); v4[3] = f2bf(acc[mi][ni][3]);
        *(ushortx4*)(vdst + n0 + mi * 16) = v4;
      }
    }
  } else if (Cb){
    #pragma unroll
    for (int ni = 0; ni < 4; ni++){
      size_t col = bn + wn + ni * 16 + fm;
      float bv = bias ? bias[col] : 0.f;
      #pragma unroll
      for (int mi = 0; mi < 4; mi++){
        #pragma unroll
        for (int r = 0; r < 4; r++){
          size_t row = bm + wm + mi * 16 + rq + r;
          float v = acc[mi][ni][r] + bv;
          if (dogelu) v = fast_gelu(v);
          size_t idx2 = row * N + col;
          if (Rb) v += bf2f(((const ushort*)Rb)[idx2]);
          Cb[idx2] = __float2bfloat16(v);
        }
      }
    }
  } else {
    #pragma unroll
    for (int ni = 0; ni < 4; ni++){
      size_t col = bn + wn + ni * 16 + fm;
      float bv = bias ? bias[col] : 0.f;
      #pragma unroll
      for (int mi = 0; mi < 4; mi++){
        #pragma unroll
        for (int r = 0; r < 4; r++){
          size_t row = bm + wm + mi * 16 + rq + r;
          float v = acc[mi][ni][r] + bv;
          if (dogelu) v = fast_gelu(v);
          size_t idx2 = row * N + col;
          if (Rb) v += bf2f(((const ushort*)Rb)[idx2]);
          Cf[idx2] = v;
        }
      }
    }
  }
}

// MFMA flash attention (round-4 structure, unchanged).
#define SC2 0.18033688011112042f   // 0.125 * log2(e)
__global__ __launch_bounds__(256) void attn_mfma(const __hip_bfloat16* __restrict__ qkvp,
                                                 const ushort* __restrict__ vt,
                                                 __hip_bfloat16* __restrict__ outp){
  __shared__ ushort Ks[64 * 64];
  __shared__ ushort Vs[64 * 64];
  __shared__ ushort Ps[4][32 * 72];
  int tid = threadIdx.x;
  int w = tid >> 6, l = tid & 63;
  int r15 = l & 15, quad = l >> 4, fq = quad * 8;
  int slice = blockIdx.x & 127;
  int qc = blockIdx.x >> 7;
  int b = slice >> 6, hh = (slice >> 3) & 7, p = slice & 7;
  const ushort* base = (const ushort*)qkvp + (size_t)(b * PPV + p) * NSEQ * QKVW;
  const ushort* kb = base + 512 + hh * DHEAD;
  const ushort* vb = vt + (size_t)slice * 65536;

  int q0 = qc * 128 + w * 32;
  short8 qf[2][2];
  #pragma unroll
  for (int mi = 0; mi < 2; mi++)
    #pragma unroll
    for (int kk = 0; kk < 2; kk++)
      qf[mi][kk] = *(const short8*)(base + (size_t)(q0 + mi * 16 + r15) * QKVW + hh * DHEAD + kk * 32 + fq);

  floatx4 o[2][4] = {};
  floatx4 lacc[2] = {};
  short8 ones;
  #pragma unroll
  for (int j = 0; j < 8; j++) ones[j] = (short)0x3F80;

  int s0 = w * 64 + l, s1 = 256 + w * 64 + l;
  int row0 = s0 >> 3, row1 = s1 >> 3;
  int gc0 = (s0 & 7) ^ (row0 & 7), gc1 = (s1 & 7) ^ (row1 & 7);
  const ushort* kp0 = kb + (size_t)row0 * QKVW + gc0 * 8;
  const ushort* kp1 = kb + (size_t)row1 * QKVW + gc1 * 8;
  const ushort* vp0 = vb + (size_t)row0 * 1024 + gc0 * 8;
  const ushort* vp1 = vb + (size_t)row1 * 1024 + gc1 * 8;
  ushort* kd0 = &Ks[s0 * 8]; ushort* kd1 = &Ks[s1 * 8];
  ushort* vd0 = &Vs[s0 * 8]; ushort* vd1 = &Vs[s1 * 8];

  int sw = r15 & 7;

  for (int m0 = 0; m0 < NSEQ; m0 += 64){
    async_copy16(kp0 + (size_t)m0 * QKVW, kd0);
    async_copy16(kp1 + (size_t)m0 * QKVW, kd1);
    async_copy16(vp0 + m0, vd0);
    async_copy16(vp1 + m0, vd1);
    __syncthreads();

    floatx4 s[2][4] = {};
    #pragma unroll
    for (int ni = 0; ni < 4; ni++){
      int row = ni * 16 + r15;
      short8 kf0 = *(const short8*)&Ks[row * 64 + (quad ^ sw) * 8];
      short8 kf1 = *(const short8*)&Ks[row * 64 + ((4 + quad) ^ sw) * 8];
      #pragma unroll
      for (int mi = 0; mi < 2; mi++){
        s[mi][ni] = __builtin_amdgcn_mfma_f32_16x16x32_bf16(qf[mi][0], kf0, s[mi][ni], 0, 0, 0);
        s[mi][ni] = __builtin_amdgcn_mfma_f32_16x16x32_bf16(qf[mi][1], kf1, s[mi][ni], 0, 0, 0);
      }
    }

    #pragma unroll
    for (int mi = 0; mi < 2; mi++)
      #pragma unroll
      for (int ni = 0; ni < 4; ni++)
        #pragma unroll
        for (int r = 0; r < 4; r++){
          float pv = exp2f(s[mi][ni][r] * SC2);
          Ps[w][(mi * 16 + quad * 4 + r) * 72 + ni * 16 + r15] = f2bf(pv);
        }

    short8 pf[2][2];
    #pragma unroll
    for (int mi = 0; mi < 2; mi++)
      #pragma unroll
      for (int kk = 0; kk < 2; kk++)
        pf[mi][kk] = *(const short8*)&Ps[w][(mi * 16 + r15) * 72 + kk * 32 + fq];

    #pragma unroll
    for (int mi = 0; mi < 2; mi++)
      #pragma unroll
      for (int kk = 0; kk < 2; kk++)
        lacc[mi] = __builtin_amdgcn_mfma_f32_16x16x32_bf16(pf[mi][kk], ones, lacc[mi], 0, 0, 0);

    #pragma unroll
    for (int dj = 0; dj < 4; dj++){
      int d = dj * 16 + r15;
      #pragma unroll
      for (int kk = 0; kk < 2; kk++){
        short8 vf = *(const short8*)&Vs[d * 64 + (((kk * 4 + quad)) ^ sw) * 8];
        #pragma unroll
        for (int mi = 0; mi < 2; mi++)
          o[mi][dj] = __builtin_amdgcn_mfma_f32_16x16x32_bf16(pf[mi][kk], vf, o[mi][dj], 0, 0, 0);
      }
    }
    __syncthreads();
  }

  #pragma unroll
  for (int mi = 0; mi < 2; mi++){
    #pragma unroll
    for (int r = 0; r < 4; r++){
      float inv = 1.f / lacc[mi][r];
      size_t n = q0 + mi * 16 + quad * 4 + r;
      ushort* orow = (ushort*)outp + ((size_t)((b * HEADSV + hh) * NSEQ + n)) * DIMV + p * DHEAD;
      #pragma unroll
      for (int dj = 0; dj < 4; dj++)
        orow[dj * 16 + r15] = f2bf(o[mi][dj][r] * inv);
    }
  }
}

extern "C" void kernel_launch(void* const* d_in, const int* in_sizes, int n_in,
                              void* d_out, int out_size, void* d_ws, size_t ws_size,
                              hipStream_t stream){
  (void)in_sizes; (void)n_in; (void)out_size; (void)ws_size;
  const float* x    = (const float*)d_in[0];
  const float* lw0  = (const float*)d_in[1];
  const float* lb0  = (const float*)d_in[2];
  const float* lw1  = (const float*)d_in[3];
  const float* lb1  = (const float*)d_in[4];
  const float* wqkv = (const float*)d_in[5];
  const float* wo   = (const float*)d_in[6];
  const float* bo   = (const float*)d_in[7];
  const float* w1   = (const float*)d_in[8];
  const float* b1   = (const float*)d_in[9];
  const float* w2   = (const float*)d_in[10];
  const float* b2   = (const float*)d_in[11];
  float* out = (float*)d_out;
  char* ws = (char*)d_ws;
  const size_t MB = 1024 * 1024;

  // Workspace (peak 152 MB):
  // [0,16)    x1b bf16 (LN0 out; residual for wo-GEMM)
  // [32,48)   vt bf16 (V transposed; written by qkv GEMM)
  // [64,80)   x2b bf16 (wo-GEMM out; residual for final GEMM)
  // [80,87)   transposed bf16 weights
  // [88,104)  h bf16 -> attnB bf16
  // [104,152) qkv bf16 (V third unused); tB spans [88,152) later
  __hip_bfloat16* x1b  = (__hip_bfloat16*)(ws);
  ushort* vtbuf        = (ushort*)(ws + 32 * MB);
  __hip_bfloat16* x2b  = (__hip_bfloat16*)(ws + 64 * MB);
  __hip_bfloat16* wqkvT= (__hip_bfloat16*)(ws + 80 * MB);
  __hip_bfloat16* woT  = (__hip_bfloat16*)(ws + 82 * MB);
  __hip_bfloat16* w1T  = (__hip_bfloat16*)(ws + 83 * MB);
  __hip_bfloat16* w2T  = (__hip_bfloat16*)(ws + 85 * MB);
  __hip_bfloat16* hB   = (__hip_bfloat16*)(ws + 88 * MB);
  __hip_bfloat16* attnB= hB;
  __hip_bfloat16* qkvB = (__hip_bfloat16*)(ws + 104 * MB);
  __hip_bfloat16* tB   = (__hip_bfloat16*)(ws + 88 * MB);

  // 1) fused prep: LN (16384 blocks) + 4 weight transposes (3072 blocks)
  prep_kernel<<<NTOK + 3072, 256, 0, stream>>>(
      x, lw0, lb0, lw1, lb1, x1b, hB,
      wqkv, wqkvT, wo, woT, w1, w1T, w2, w2T);

  // 2) qkv = h @ w_qkv -> bf16 (Q,K) + transposed V into vtbuf
  gemm_mfma<<<(QKVW / 128) * 128, 256, 0, stream>>>(
      hB, wqkvT, nullptr, nullptr, nullptr, qkvB, vtbuf,
      NTOK, QKVW, DIMV, QKVW / 128, 0);

  // 3) attention
  attn_mfma<<<1024, 256, 0, stream>>>(qkvB, vtbuf, attnB);

  // 4) x2b = attn @ w_o + b_o + x1b -> bf16
  gemm_mfma<<<(DIMV / 128) * 128, 256, 0, stream>>>(
      attnB, woT, bo, x1b, nullptr, x2b, nullptr,
      NTOK, DIMV, DIMV, DIMV / 128, 0);

  // 5) t = gelu_fast(x2b @ w1 + b1) -> bf16
  gemm_mfma<<<(HIDV / 128) * 128, 256, 0, stream>>>(
      x2b, w1T, b1, nullptr, nullptr, tB, nullptr,
      NTOK, HIDV, DIMV, HIDV / 128, 1);

  // 6) out = t @ w2 + b2 + x2b -> fp32
  gemm_mfma<<<(DIMV / 128) * 128, 256, 0, stream>>>(
      tB, w2T, b2, x2b, out, nullptr, nullptr,
      NTOK, DIMV, HIDV, DIMV / 128, 0);
}

// Round 9
// 419.055 us; speedup vs baseline: 1.4405x; 1.0064x over previous
//
#include <hip/hip_runtime.h>
#include <hip/hip_bf16.h>
#include <math.h>

#define DIMV 512
#define NTOK 16384   // B*P*N = 2*8*1024
#define NSEQ 1024
#define HEADSV 8
#define PPV 8
#define DHEAD 64
#define QKVW 1536
#define HIDV 2048
#define SC2 0.18033688011112042f   // 0.125 * log2(e)

typedef unsigned short ushort;
typedef __attribute__((ext_vector_type(8))) short short8;
typedef __attribute__((ext_vector_type(8))) unsigned short ushort8;
typedef __attribute__((ext_vector_type(4))) unsigned short ushortx4;
typedef __attribute__((ext_vector_type(4))) float floatx4;

__device__ __forceinline__ float bf2f(ushort u){
  union { unsigned int i; float f; } c; c.i = ((unsigned int)u) << 16; return c.f;
}
// fast RNE f32->bf16 (finite values; no NaN branch): 3 VALU
__device__ __forceinline__ ushort f2bf(float f){
  union { float f; unsigned int i; } c; c.f = f;
  unsigned int u = c.i + 0x7fffu + ((c.i >> 16) & 1u);
  return (ushort)(u >> 16);
}
// truncating f32->bf16 (1 VALU) — for P only (bias cancels in softmax ratio)
__device__ __forceinline__ ushort f2bf_t(float f){
  union { float f; unsigned int i; } c; c.f = f;
  return (ushort)(c.i >> 16);
}
__device__ __forceinline__ void async_copy16(const void* gptr, void* lptr){
  __builtin_amdgcn_global_load_lds((const __attribute__((address_space(1))) void*)gptr,
                                   (__attribute__((address_space(3))) void*)lptr, 16, 0, 0);
}
// tanh-form GELU via one v_exp_f32: x * sigmoid(1.5957691x + 0.0713548x^3)
__device__ __forceinline__ float fast_gelu(float x){
  float u = x * (2.3022084f + 0.1029435f * x * x);   // (2u)*log2(e)
  return x * __builtin_amdgcn_rcpf(1.f + exp2f(-u));
}

__device__ __forceinline__ void wave_reduce2(float& a, float& b){
  #pragma unroll
  for (int off = 32; off > 0; off >>= 1){
    a += __shfl_down(a, off, 64);
    b += __shfl_down(b, off, 64);
  }
}

// ---- fused prep kernel: LN (blocks [0,16384)) + 4 weight transposes ----
__device__ __forceinline__ void wtrans_body(const float* __restrict__ W,
    __hip_bfloat16* __restrict__ Wt, int K, int N, int bx, int by, int t,
    float* tile /* 32*33 */){
  int bn = bx * 32, bk = by * 32;
  int tx = t & 31, ty = t >> 5;
  #pragma unroll
  for (int i = 0; i < 32; i += 8)
    tile[(ty + i) * 33 + tx] = W[(size_t)(bk + ty + i) * N + bn + tx];
  __syncthreads();
  #pragma unroll
  for (int i = 0; i < 32; i += 8)
    Wt[(size_t)(bn + ty + i) * K + bk + tx] = __float2bfloat16(tile[tx * 33 + ty + i]);
}

__global__ __launch_bounds__(256) void prep_kernel(const float* __restrict__ x,
    const float* __restrict__ w0, const float* __restrict__ b0,
    const float* __restrict__ w1ln, const float* __restrict__ b1ln,
    __hip_bfloat16* __restrict__ x1, __hip_bfloat16* __restrict__ h,
    const float* __restrict__ wqkv, __hip_bfloat16* __restrict__ wqkvT,
    const float* __restrict__ wo,   __hip_bfloat16* __restrict__ woT,
    const float* __restrict__ w1,   __hip_bfloat16* __restrict__ w1T,
    const float* __restrict__ w2,   __hip_bfloat16* __restrict__ w2T){
  __shared__ float smem[32 * 33];
  int bid = blockIdx.x;
  int t = threadIdx.x;
  if (bid >= NTOK){
    int r = bid - NTOK;
    if (r < 768)        wtrans_body(wqkv, wqkvT, 512, 1536, r % 48, r / 48, t, smem);
    else if (r < 1024){ r -= 768;  wtrans_body(wo, woT, 512, 512,  r % 16, r / 16, t, smem); }
    else if (r < 2048){ r -= 1024; wtrans_body(w1, w1T, 512, 2048, r % 64, r / 64, t, smem); }
    else             { r -= 2048; wtrans_body(w2, w2T, 2048, 512, r % 16, r / 16, t, smem); }
    return;
  }
  // ---- double LN ----
  float* sm = smem;
  size_t row = bid;
  const float2* xr = (const float2*)(x + row * DIMV);
  float2 v = xr[t];
  float s = v.x + v.y;
  float sq = v.x * v.x + v.y * v.y;
  wave_reduce2(s, sq);
  int wid = t >> 6, lane = t & 63;
  if (lane == 0){ sm[wid] = s; sm[8 + wid] = sq; }
  __syncthreads();
  s  = sm[0] + sm[1] + sm[2] + sm[3];
  sq = sm[8] + sm[9] + sm[10] + sm[11];
  float mu = s * (1.f / DIMV);
  float var = sq * (1.f / DIMV) - mu * mu;
  float r = rsqrtf(var + 1e-5f);
  float2 ww = ((const float2*)w0)[t];
  float2 bb = ((const float2*)b0)[t];
  float2 y;
  y.x = (v.x - mu) * r * ww.x + bb.x;
  y.y = (v.y - mu) * r * ww.y + bb.y;
  ushort2 xb; xb.x = f2bf(y.x); xb.y = f2bf(y.y);
  ((ushort2*)(x1 + row * DIMV))[t] = xb;
  float s2 = y.x + y.y, sq2 = y.x * y.x + y.y * y.y;
  wave_reduce2(s2, sq2);
  __syncthreads();
  if (lane == 0){ sm[wid] = s2; sm[8 + wid] = sq2; }
  __syncthreads();
  s2  = sm[0] + sm[1] + sm[2] + sm[3];
  sq2 = sm[8] + sm[9] + sm[10] + sm[11];
  float mu2 = s2 * (1.f / DIMV);
  float var2 = sq2 * (1.f / DIMV) - mu2 * mu2;
  float r2 = rsqrtf(var2 + 1e-5f);
  float2 w1v = ((const float2*)w1ln)[t];
  float2 b1v = ((const float2*)b1ln)[t];
  float hx = (y.x - mu2) * r2 * w1v.x + b1v.x;
  float hy = (y.y - mu2) * r2 * w1v.y + b1v.y;
  ushort2 hb; hb.x = f2bf(hx); hb.y = f2bf(hy);
  ((ushort2*)(h + row * DIMV))[t] = hb;
}

// MFMA bf16 GEMM: BK=32, 128x128 tile, XCD-swizzled 1D grid.
// C = A[M,K] @ Bt[N,K]^T (+bias)(gelu?)(+Rb bf16) -> Cf fp32 or Cb bf16.
// If vt != null (qkv GEMM): bn >= 1024 (V cols) -> transposed store into vt;
// bn < 512 (Q cols) -> pre-scaled by SC2 (attention softmax scale folded in).
__global__ __launch_bounds__(256) void gemm_mfma(
    const __hip_bfloat16* __restrict__ A,
    const __hip_bfloat16* __restrict__ Bt,
    const float* __restrict__ bias,
    const __hip_bfloat16* __restrict__ Rb,
    float* __restrict__ Cf,
    __hip_bfloat16* __restrict__ Cb,
    ushort* __restrict__ vt,
    int M, int N, int K, int gx, int dogelu)
{
  __shared__ __hip_bfloat16 As[128 * 32];
  __shared__ __hip_bfloat16 Bs[128 * 32];
  int tid = threadIdx.x;
  int w = tid >> 6, l = tid & 63;

  int bid = blockIdx.x;
  int xcd = bid & 7, idx = bid >> 3;
  int xl = idx % gx, yl = idx / gx;
  size_t bm = (size_t)(xcd * 16 + yl) * 128;
  size_t bn = (size_t)xl * 128;
  int wm = (w & 1) * 64, wn = (w >> 1) * 64;

  int srow = w * 16 + (l >> 2);
  int scol = (l & 3) * 8;
  const __hip_bfloat16* Ag0 = A + (bm + srow) * K + scol;
  const __hip_bfloat16* Ag1 = A + (bm + 64 + srow) * K + scol;
  const __hip_bfloat16* Bg0 = Bt + (bn + srow) * K + scol;
  const __hip_bfloat16* Bg1 = Bt + (bn + 64 + srow) * K + scol;
  __hip_bfloat16* lA0 = &As[srow * 32 + scol];
  __hip_bfloat16* lA1 = &As[(64 + srow) * 32 + scol];
  __hip_bfloat16* lB0 = &Bs[srow * 32 + scol];
  __hip_bfloat16* lB1 = &Bs[(64 + srow) * 32 + scol];

  floatx4 acc[4][4] = {};
  int fm = l & 15;
  int quad = l >> 4;
  int fq = quad * 8;

  for (int k0 = 0; k0 < K; k0 += 32){
    async_copy16(Ag0 + k0, lA0);
    async_copy16(Ag1 + k0, lA1);
    async_copy16(Bg0 + k0, lB0);
    async_copy16(Bg1 + k0, lB1);
    __syncthreads();
    short8 af[4], bf[4];
    #pragma unroll
    for (int i = 0; i < 4; i++){
      af[i] = *(const short8*)&As[(wm + i * 16 + fm) * 32 + fq];
      bf[i] = *(const short8*)&Bs[(wn + i * 16 + fm) * 32 + fq];
    }
    #pragma unroll
    for (int mi = 0; mi < 4; mi++)
      #pragma unroll
      for (int ni = 0; ni < 4; ni++)
        acc[mi][ni] = __builtin_amdgcn_mfma_f32_16x16x32_bf16(af[mi], bf[ni], acc[mi][ni], 0, 0, 0);
    __syncthreads();
  }

  // C/D layout: col = l&15, row = quad*4 + reg
  int rq = quad * 4;
  if (vt && bn >= 1024){
    // ---- qkv V-columns: write transposed into vt[slice][d][n] ----
    int b = (int)(bm >> 13), p = (int)((bm >> 10) & 7);
    int n0 = (int)(bm & 1023) + wm + rq;
    int cbase = (int)bn + wn - 1024;
    #pragma unroll
    for (int ni = 0; ni < 4; ni++){
      int cc = cbase + ni * 16 + fm;
      int hh = cc >> 6, dd = cc & 63;
      ushort* vdst = vt + ((size_t)((b * 8 + hh) * 8 + p)) * 65536 + (size_t)dd * 1024;
      #pragma unroll
      for (int mi = 0; mi < 4; mi++){
        ushortx4 v4;
        v4[0] = f2bf(acc[mi][ni][0]); v4[1] = f2bf(acc[mi][ni][1]);
        v4[2] = f2bf(acc[mi][ni][2]); v4[3] = f2bf(acc[mi][ni][3]);
        *(ushortx4*)(vdst + n0 + mi * 16) = v4;
      }
    }
  } else if (Cb){
    float scl = (vt && bn < 512) ? SC2 : 1.f;
    #pragma unroll
    for (int ni = 0; ni < 4; ni++){
      size_t col = bn + wn + ni * 16 + fm;
      float bv = bias ? bias[col] : 0.f;
      #pragma unroll
      for (int mi = 0; mi < 4; mi++){
        #pragma unroll
        for (int r = 0; r < 4; r++){
          size_t row = bm + wm + mi * 16 + rq + r;
          float v = acc[mi][ni][r];
          if (vt) v *= scl;
          v += bv;
          if (dogelu) v = fast_gelu(v);
          size_t idx2 = row * N + col;
          if (Rb) v += bf2f(((const ushort*)Rb)[idx2]);
          Cb[idx2] = __hip_bfloat16(); // placeholder overwritten below
          ((ushort*)Cb)[idx2] = f2bf(v);
        }
      }
    }
  } else {
    #pragma unroll
    for (int ni = 0; ni < 4; ni++){
      size_t col = bn + wn + ni * 16 + fm;
      float bv = bias ? bias[col] : 0.f;
      #pragma unroll
      for (int mi = 0; mi < 4; mi++){
        #pragma unroll
        for (int r = 0; r < 4; r++){
          size_t row = bm + wm + mi * 16 + rq + r;
          float v = acc[mi][ni][r] + bv;
          if (dogelu) v = fast_gelu(v);
          size_t idx2 = row * N + col;
          if (Rb) v += bf2f(((const ushort*)Rb)[idx2]);
          Cf[idx2] = v;
        }
      }
    }
  }
}

// MFMA flash attention. Q pre-scaled by SC2 (folded into qkv GEMM).
__global__ __launch_bounds__(256) void attn_mfma(const __hip_bfloat16* __restrict__ qkvp,
                                                 const ushort* __restrict__ vt,
                                                 __hip_bfloat16* __restrict__ outp){
  __shared__ ushort Ks[64 * 64];
  __shared__ ushort Vs[64 * 64];
  __shared__ ushort Ps[4][32 * 72];
  int tid = threadIdx.x;
  int w = tid >> 6, l = tid & 63;
  int r15 = l & 15, quad = l >> 4, fq = quad * 8;
  int slice = blockIdx.x & 127;
  int qc = blockIdx.x >> 7;
  int b = slice >> 6, hh = (slice >> 3) & 7, p = slice & 7;
  const ushort* base = (const ushort*)qkvp + (size_t)(b * PPV + p) * NSEQ * QKVW;
  const ushort* kb = base + 512 + hh * DHEAD;
  const ushort* vb = vt + (size_t)slice * 65536;

  int q0 = qc * 128 + w * 32;
  short8 qf[2][2];
  #pragma unroll
  for (int mi = 0; mi < 2; mi++)
    #pragma unroll
    for (int kk = 0; kk < 2; kk++)
      qf[mi][kk] = *(const short8*)(base + (size_t)(q0 + mi * 16 + r15) * QKVW + hh * DHEAD + kk * 32 + fq);

  floatx4 o[2][4] = {};
  floatx4 lacc[2] = {};
  short8 ones;
  #pragma unroll
  for (int j = 0; j < 8; j++) ones[j] = (short)0x3F80;

  int s0 = w * 64 + l, s1 = 256 + w * 64 + l;
  int row0 = s0 >> 3, row1 = s1 >> 3;
  int gc0 = (s0 & 7) ^ (row0 & 7), gc1 = (s1 & 7) ^ (row1 & 7);
  const ushort* kp0 = kb + (size_t)row0 * QKVW + gc0 * 8;
  const ushort* kp1 = kb + (size_t)row1 * QKVW + gc1 * 8;
  const ushort* vp0 = vb + (size_t)row0 * 1024 + gc0 * 8;
  const ushort* vp1 = vb + (size_t)row1 * 1024 + gc1 * 8;
  ushort* kd0 = &Ks[s0 * 8]; ushort* kd1 = &Ks[s1 * 8];
  ushort* vd0 = &Vs[s0 * 8]; ushort* vd1 = &Vs[s1 * 8];

  int sw = r15 & 7;

  for (int m0 = 0; m0 < NSEQ; m0 += 64){
    async_copy16(kp0 + (size_t)m0 * QKVW, kd0);
    async_copy16(kp1 + (size_t)m0 * QKVW, kd1);
    async_copy16(vp0 + m0, vd0);
    async_copy16(vp1 + m0, vd1);
    __syncthreads();

    floatx4 s[2][4] = {};
    #pragma unroll
    for (int ni = 0; ni < 4; ni++){
      int row = ni * 16 + r15;
      short8 kf0 = *(const short8*)&Ks[row * 64 + (quad ^ sw) * 8];
      short8 kf1 = *(const short8*)&Ks[row * 64 + ((4 + quad) ^ sw) * 8];
      #pragma unroll
      for (int mi = 0; mi < 2; mi++){
        s[mi][ni] = __builtin_amdgcn_mfma_f32_16x16x32_bf16(qf[mi][0], kf0, s[mi][ni], 0, 0, 0);
        s[mi][ni] = __builtin_amdgcn_mfma_f32_16x16x32_bf16(qf[mi][1], kf1, s[mi][ni], 0, 0, 0);
      }
    }

    // P = exp2(S) (Q pre-scaled); truncating bf16 (bias cancels via l from P)
    #pragma unroll
    for (int mi = 0; mi < 2; mi++)
      #pragma unroll
      for (int ni = 0; ni < 4; ni++)
        #pragma unroll
        for (int r = 0; r < 4; r++)
          Ps[w][(mi * 16 + quad * 4 + r) * 72 + ni * 16 + r15] = f2bf_t(exp2f(s[mi][ni][r]));

    short8 pf[2][2];
    #pragma unroll
    for (int mi = 0; mi < 2; mi++)
      #pragma unroll
      for (int kk = 0; kk < 2; kk++)
        pf[mi][kk] = *(const short8*)&Ps[w][(mi * 16 + r15) * 72 + kk * 32 + fq];

    #pragma unroll
    for (int mi = 0; mi < 2; mi++)
      #pragma unroll
      for (int kk = 0; kk < 2; kk++)
        lacc[mi] = __builtin_amdgcn_mfma_f32_16x16x32_bf16(pf[mi][kk], ones, lacc[mi], 0, 0, 0);

    #pragma unroll
    for (int dj = 0; dj < 4; dj++){
      int d = dj * 16 + r15;
      #pragma unroll
      for (int kk = 0; kk < 2; kk++){
        short8 vf = *(const short8*)&Vs[d * 64 + (((kk * 4 + quad)) ^ sw) * 8];
        #pragma unroll
        for (int mi = 0; mi < 2; mi++)
          o[mi][dj] = __builtin_amdgcn_mfma_f32_16x16x32_bf16(pf[mi][kk], vf, o[mi][dj], 0, 0, 0);
      }
    }
    __syncthreads();
  }

  #pragma unroll
  for (int mi = 0; mi < 2; mi++){
    #pragma unroll
    for (int r = 0; r < 4; r++){
      float inv = __builtin_amdgcn_rcpf(lacc[mi][r]);
      size_t n = q0 + mi * 16 + quad * 4 + r;
      ushort* orow = (ushort*)outp + ((size_t)((b * HEADSV + hh) * NSEQ + n)) * DIMV + p * DHEAD;
      #pragma unroll
      for (int dj = 0; dj < 4; dj++)
        orow[dj * 16 + r15] = f2bf(o[mi][dj][r] * inv);
    }
  }
}

extern "C" void kernel_launch(void* const* d_in, const int* in_sizes, int n_in,
                              void* d_out, int out_size, void* d_ws, size_t ws_size,
                              hipStream_t stream){
  (void)in_sizes; (void)n_in; (void)out_size; (void)ws_size;
  const float* x    = (const float*)d_in[0];
  const float* lw0  = (const float*)d_in[1];
  const float* lb0  = (const float*)d_in[2];
  const float* lw1  = (const float*)d_in[3];
  const float* lb1  = (const float*)d_in[4];
  const float* wqkv = (const float*)d_in[5];
  const float* wo   = (const float*)d_in[6];
  const float* bo   = (const float*)d_in[7];
  const float* w1   = (const float*)d_in[8];
  const float* b1   = (const float*)d_in[9];
  const float* w2   = (const float*)d_in[10];
  const float* b2   = (const float*)d_in[11];
  float* out = (float*)d_out;
  char* ws = (char*)d_ws;
  const size_t MB = 1024 * 1024;

  __hip_bfloat16* x1b  = (__hip_bfloat16*)(ws);
  ushort* vtbuf        = (ushort*)(ws + 32 * MB);
  __hip_bfloat16* x2b  = (__hip_bfloat16*)(ws + 64 * MB);
  __hip_bfloat16* wqkvT= (__hip_bfloat16*)(ws + 80 * MB);
  __hip_bfloat16* woT  = (__hip_bfloat16*)(ws + 82 * MB);
  __hip_bfloat16* w1T  = (__hip_bfloat16*)(ws + 83 * MB);
  __hip_bfloat16* w2T  = (__hip_bfloat16*)(ws + 85 * MB);
  __hip_bfloat16* hB   = (__hip_bfloat16*)(ws + 88 * MB);
  __hip_bfloat16* attnB= hB;
  __hip_bfloat16* qkvB = (__hip_bfloat16*)(ws + 104 * MB);
  __hip_bfloat16* tB   = (__hip_bfloat16*)(ws + 88 * MB);

  // 1) fused prep: LN (16384 blocks) + 4 weight transposes (3072 blocks)
  prep_kernel<<<NTOK + 3072, 256, 0, stream>>>(
      x, lw0, lb0, lw1, lb1, x1b, hB,
      wqkv, wqkvT, wo, woT, w1, w1T, w2, w2T);

  // 2) qkv = h @ w_qkv -> bf16 (Q scaled by SC2, K) + transposed V into vtbuf
  gemm_mfma<<<(QKVW / 128) * 128, 256, 0, stream>>>(
      hB, wqkvT, nullptr, nullptr, nullptr, qkvB, vtbuf,
      NTOK, QKVW, DIMV, QKVW / 128, 0);

  // 3) attention
  attn_mfma<<<1024, 256, 0, stream>>>(qkvB, vtbuf, attnB);

  // 4) x2b = attn @ w_o + b_o + x1b -> bf16
  gemm_mfma<<<(DIMV / 128) * 128, 256, 0, stream>>>(
      attnB, woT, bo, x1b, nullptr, x2b, nullptr,
      NTOK, DIMV, DIMV, DIMV / 128, 0);

  // 5) t = gelu_fast(x2b @ w1 + b1) -> bf16
  gemm_mfma<<<(HIDV / 128) * 128, 256, 0, stream>>>(
      x2b, w1T, b1, nullptr, nullptr, tB, nullptr,
      NTOK, HIDV, DIMV, HIDV / 128, 1);

  // 6) out = t @ w2 + b2 + x2b -> fp32
  gemm_mfma<<<(DIMV / 128) * 128, 256, 0, stream>>>(
      tB, w2T, b2, x2b, out, nullptr, nullptr,
      NTOK, DIMV, HIDV, DIMV / 128, 0);
}